// Round 5
// baseline (552.521 us; speedup 1.0000x reference)
//
#include <hip/hip_runtime.h>
#include <math.h>

#define NN 25000      // nodes
#define NE 400000     // edges
#define DD 128        // hidden dim
#define HD 384        // heads * dim
#define NEG 0.2f
#define EPS 1e-5f

typedef unsigned int u32;
typedef unsigned short u16;
typedef __attribute__((ext_vector_type(8))) short short8;   // 8 bf16 (4 VGPRs)
typedef __attribute__((ext_vector_type(4))) float floatx4;  // MFMA accumulator

// ---- bf16 helpers (RNE) ----
__device__ __forceinline__ u32 bf16_1(float x) {
    u32 u = __float_as_uint(x);
    return (u + 0x7fffu + ((u >> 16) & 1u)) >> 16;
}
__device__ __forceinline__ float blo(u32 u) { return __uint_as_float(u << 16); }
__device__ __forceinline__ float bhi(u32 u) { return __uint_as_float(u & 0xffff0000u); }

__device__ __forceinline__ void up8(uint4 u, float* f) {
    f[0] = blo(u.x); f[1] = bhi(u.x); f[2] = blo(u.y); f[3] = bhi(u.y);
    f[4] = blo(u.z); f[5] = bhi(u.z); f[6] = blo(u.w); f[7] = bhi(u.w);
}

// ---- DPP 16-lane butterfly sum (VALU pipe, no LDS) ----
template<int CTRL>
__device__ __forceinline__ float dpp_add(float x) {
    int t = __builtin_amdgcn_update_dpp(0, __float_as_int(x), CTRL, 0xF, 0xF, true);
    return x + __int_as_float(t);
}
__device__ __forceinline__ float red16(float x) {
    x = dpp_add<0xB1>(x);    // quad_perm(1,0,3,2)  = xor1
    x = dpp_add<0x4E>(x);    // quad_perm(2,3,0,1)  = xor2
    x = dpp_add<0x141>(x);   // row_half_mirror     (xor4 on quad-uniform)
    x = dpp_add<0x140>(x);   // row_mirror          (xor8 on half-uniform)
    return x;
}

// ---------------- CSR construction (grouped by dst) ----------------

__global__ void k_count(const int* __restrict__ dst, int* __restrict__ cnt) {
    int e = blockIdx.x * 256 + threadIdx.x;
    if (e < NE) atomicAdd(&cnt[dst[e]], 1);
}

// one-kernel scan + self-loop fill: 1024 threads, 25 elems/thread
__global__ void k_scan_all(const int* __restrict__ cnt, int* __restrict__ row_ptr,
                           int* __restrict__ col_src, int* __restrict__ cur) {
    __shared__ int sh[1024];
    const int CH = 25;
    int t = threadIdx.x;
    int beg = t * CH, end = beg + CH < NN ? beg + CH : NN;
    int s = 0;
    for (int i = beg; i < end; ++i) s += cnt[i];
    sh[t] = s;
    __syncthreads();
    for (int o = 1; o < 1024; o <<= 1) {
        int v = (t >= o) ? sh[t - o] : 0;
        __syncthreads();
        sh[t] += v;
        __syncthreads();
    }
    int run = (t > 0) ? sh[t - 1] : 0;   // exclusive prefix of this chunk
    for (int i = beg; i < end; ++i) {
        int v = cnt[i];
        row_ptr[i + 1] = run + v;
        col_src[run] = i;                // self loop first
        cur[i] = run + 1;
        run += v;
    }
    if (t == 0) row_ptr[0] = 0;
}

__global__ void k_fill_edges(const int* __restrict__ src, const int* __restrict__ dst,
                             int* __restrict__ cur, int* __restrict__ col_src) {
    int e = blockIdx.x * 256 + threadIdx.x;
    if (e < NE) { int p = atomicAdd(&cur[dst[e]], 1); col_src[p] = src[e]; }
}

// ---------------- one cast/init kernel for everything ----------------
__global__ void k_cast_all(const float* __restrict__ x,
                           const float* __restrict__ Wl1, const float* __restrict__ Wr1,
                           const float* __restrict__ W1,
                           const float* __restrict__ Wl2, const float* __restrict__ Wr2,
                           const float* __restrict__ W2,
                           const float* __restrict__ bl1, const float* __restrict__ br1,
                           const float* __restrict__ bl2, const float* __restrict__ br2,
                           u16* __restrict__ xb, u16* __restrict__ WfT1,
                           u16* __restrict__ W1T, u16* __restrict__ WfT2,
                           u16* __restrict__ W2T,
                           float* __restrict__ fb1, float* __restrict__ fb2,
                           int* __restrict__ cnt, float* __restrict__ stats) {
    int i = blockIdx.x * 256 + threadIdx.x;
    if (i < 3200000) { xb[i] = (u16)bf16_1(x[i]); return; }
    i -= 3200000;
    if (i < 49152) { int k = i / 384, n = i - k * 384; WfT1[n * 128 + k] = (u16)bf16_1(Wl1[i]); return; }
    i -= 49152;
    if (i < 49152) { int k = i / 384, n = i - k * 384; WfT1[(384 + n) * 128 + k] = (u16)bf16_1(Wr1[i]); return; }
    i -= 49152;
    if (i < 49152) { int k = i / 128, n = i - k * 128; W1T[n * 384 + k] = (u16)bf16_1(W1[i]); return; }
    i -= 49152;
    if (i < 49152) { int k = i / 384, n = i - k * 384; WfT2[n * 128 + k] = (u16)bf16_1(Wl2[i]); return; }
    i -= 49152;
    if (i < 49152) { int k = i / 384, n = i - k * 384; WfT2[(384 + n) * 128 + k] = (u16)bf16_1(Wr2[i]); return; }
    i -= 49152;
    if (i < 98304) { int k = i / 128, n = i - k * 128; W2T[n * 768 + k] = (u16)bf16_1(W2[i]); return; }
    i -= 98304;
    if (i < 768) { fb1[i] = (i < 384) ? bl1[i] : br1[i - 384]; return; }
    i -= 768;
    if (i < 768) { fb2[i] = (i < 384) ? bl2[i] : br2[i - 384]; return; }
    i -= 768;
    if (i < 25000) { cnt[i] = 1; return; }   // self loop
    i -= 25000;
    if (i < 512) stats[i] = 0.f;
}
#define CAST_TOTAL (3200000 + 5 * 49152 + 98304 + 1536 + 25000 + 512)

// ---------------- bf16 MFMA GEMM: C[M,N] = A[M,K] @ BT[N,K]^T (+bias) ----------------
// BM=128 BN=64 BK=64, global_load_lds(16B) staging, XOR-swizzled source addressing.
__global__ __launch_bounds__(256) void k_gemm_bf(
        const u16* __restrict__ A, const u16* __restrict__ BT,
        const float* __restrict__ bias,
        float* __restrict__ Cf, u16* __restrict__ Cb,
        int M, int N, int K, int lda, int split) {
    __shared__ short sA[128 * 64];
    __shared__ short sB[64 * 64];
    int tid = threadIdx.x;
    int wv = tid >> 6, lane = tid & 63;
    int quad = lane >> 4, m16 = lane & 15;
    int sw = m16 & 7;
    int mb = blockIdx.y * 128, nb = blockIdx.x * 64;

    floatx4 acc[2][4];
#pragma unroll
    for (int mf = 0; mf < 2; ++mf)
#pragma unroll
        for (int nf = 0; nf < 4; ++nf)
#pragma unroll
            for (int r = 0; r < 4; ++r) acc[mf][nf][r] = 0.f;

    for (int k0 = 0; k0 < K; k0 += 64) {
#pragma unroll
        for (int j = 0; j < 4; ++j) {
            int L = (wv * 4 + j) * 64 + lane;
            int r = L >> 3, c8 = (L & 7) ^ (r & 7);
            int gr = mb + r; gr = gr < M ? gr : M - 1;
            __builtin_amdgcn_global_load_lds(
                (const __attribute__((address_space(1))) void*)(A + (size_t)gr * lda + k0 + c8 * 8),
                (__attribute__((address_space(3))) void*)(sA + (size_t)(wv * 4 + j) * 512),
                16, 0, 0);
        }
#pragma unroll
        for (int j = 0; j < 2; ++j) {
            int L = (wv * 2 + j) * 64 + lane;
            int r = L >> 3, c8 = (L & 7) ^ (r & 7);
            __builtin_amdgcn_global_load_lds(
                (const __attribute__((address_space(1))) void*)(BT + (size_t)(nb + r) * K + k0 + c8 * 8),
                (__attribute__((address_space(3))) void*)(sB + (size_t)(wv * 2 + j) * 512),
                16, 0, 0);
        }
        __syncthreads();
#pragma unroll
        for (int ks = 0; ks < 2; ++ks) {
            int t = (ks * 4 + quad) ^ sw;
            const short* pa = sA + t * 8;
            const short* pb = sB + t * 8;
            short8 a0 = *(const short8*)(pa + (wv * 32 + m16) * 64);
            short8 a1 = *(const short8*)(pa + (wv * 32 + 16 + m16) * 64);
            short8 b0 = *(const short8*)(pb + m16 * 64);
            short8 b1 = *(const short8*)(pb + (16 + m16) * 64);
            short8 b2 = *(const short8*)(pb + (32 + m16) * 64);
            short8 b3 = *(const short8*)(pb + (48 + m16) * 64);
            acc[0][0] = __builtin_amdgcn_mfma_f32_16x16x32_bf16(a0, b0, acc[0][0], 0, 0, 0);
            acc[0][1] = __builtin_amdgcn_mfma_f32_16x16x32_bf16(a0, b1, acc[0][1], 0, 0, 0);
            acc[0][2] = __builtin_amdgcn_mfma_f32_16x16x32_bf16(a0, b2, acc[0][2], 0, 0, 0);
            acc[0][3] = __builtin_amdgcn_mfma_f32_16x16x32_bf16(a0, b3, acc[0][3], 0, 0, 0);
            acc[1][0] = __builtin_amdgcn_mfma_f32_16x16x32_bf16(a1, b0, acc[1][0], 0, 0, 0);
            acc[1][1] = __builtin_amdgcn_mfma_f32_16x16x32_bf16(a1, b1, acc[1][1], 0, 0, 0);
            acc[1][2] = __builtin_amdgcn_mfma_f32_16x16x32_bf16(a1, b2, acc[1][2], 0, 0, 0);
            acc[1][3] = __builtin_amdgcn_mfma_f32_16x16x32_bf16(a1, b3, acc[1][3], 0, 0, 0);
        }
        __syncthreads();
    }
    u16* cbase = Cb;
    int coff = 0, ldcb = N;
    if (split) {
        ldcb = 384;
        if (nb >= 384) { cbase = Cb + (size_t)NN * 384; coff = 384; }
    }
#pragma unroll
    for (int mf = 0; mf < 2; ++mf) {
        int rbase = mb + wv * 32 + mf * 16 + quad * 4;
#pragma unroll
        for (int nf = 0; nf < 4; ++nf) {
            int col = nb + nf * 16 + m16;
            float bv = bias ? bias[col] : 0.f;
#pragma unroll
            for (int r = 0; r < 4; ++r) {
                int row = rbase + r;
                if (row < M) {
                    float v = acc[mf][nf][r] + bv;
                    if (Cf) Cf[(size_t)row * N + col] = v;
                    if (Cb) cbase[(size_t)row * ldcb + col - coff] = (u16)bf16_1(v);
                }
            }
        }
    }
}

// ---------------- GATv2 aggregate ----------------
// One wave per dst node; 4 groups of 16 lanes; each group processes edge PAIRS
// (t, t+4) per iteration with depth-1 pair prefetch => 12 outstanding dwordx4
// per wave. DPP butterfly for the 16-lane score reduce. Sentinel p=-1e30 for
// tail edges (weight becomes exactly 0). Flash-merge of 4 group states at end.
__global__ __launch_bounds__(256) void k_gat(const u32* __restrict__ XL,
                                             const u32* __restrict__ XR,
                                             const float* __restrict__ att,
                                             const float* __restrict__ bias,
                                             const int* __restrict__ row_ptr,
                                             const int* __restrict__ col_src,
                                             u32* __restrict__ outb) {
    int node = blockIdx.x * 4 + (threadIdx.x >> 6);
    int lane = threadIdx.x & 63;
    int g = lane >> 4, gl = lane & 15;

    const u32* xrp = XR + (size_t)node * 192 + 4 * gl;
    float xr_f[3][8], att_f[3][8], acc[3][8], m[3], l[3];
#pragma unroll
    for (int h = 0; h < 3; ++h) {
        up8(*(const uint4*)(xrp + h * 64), xr_f[h]);
        *(float4*)&att_f[h][0] = *(const float4*)&att[h * 128 + 8 * gl];
        *(float4*)&att_f[h][4] = *(const float4*)&att[h * 128 + 8 * gl + 4];
#pragma unroll
        for (int k = 0; k < 8; ++k) acc[h][k] = 0.f;
        m[h] = -1e30f; l[h] = 0.f;
    }

    int e0 = row_ptr[node];
    int cntE = row_ptr[node + 1] - e0;
    int elast = e0 + cntE - 1;

    // prefetch first pair (clamped — safe, cache-hot when overshooting)
    int ea = e0 + g;       ea = ea < elast ? ea : elast;
    int eb = e0 + g + 4;   eb = eb < elast ? eb : elast;
    int sa = col_src[ea], sb = col_src[eb];
    const u32* ap = XL + (size_t)sa * 192 + 4 * gl;
    const u32* bp = XL + (size_t)sb * 192 + 4 * gl;
    uint4 A0 = *(const uint4*)ap, A1 = *(const uint4*)(ap + 64), A2 = *(const uint4*)(ap + 128);
    uint4 B0 = *(const uint4*)bp, B1 = *(const uint4*)(bp + 64), B2 = *(const uint4*)(bp + 128);

    for (int t = g; t < cntE; t += 8) {
        float xa[3][8], xb[3][8];
        up8(A0, xa[0]); up8(A1, xa[1]); up8(A2, xa[2]);
        up8(B0, xb[0]); up8(B1, xb[1]); up8(B2, xb[2]);
        bool vb = (t + 4) < cntE;
        // prefetch next pair
        int tn = t + 8;
        ea = e0 + tn;     ea = ea < elast ? ea : elast;
        eb = e0 + tn + 4; eb = eb < elast ? eb : elast;
        sa = col_src[ea]; sb = col_src[eb];
        ap = XL + (size_t)sa * 192 + 4 * gl;
        bp = XL + (size_t)sb * 192 + 4 * gl;
        A0 = *(const uint4*)ap; A1 = *(const uint4*)(ap + 64); A2 = *(const uint4*)(ap + 128);
        B0 = *(const uint4*)bp; B1 = *(const uint4*)(bp + 64); B2 = *(const uint4*)(bp + 128);

        float pa[3], pb[3];
#pragma unroll
        for (int h = 0; h < 3; ++h) {
            float sa_ = 0.f, sb_ = 0.f;
#pragma unroll
            for (int k = 0; k < 8; ++k) {
                float va = xa[h][k] + xr_f[h][k];
                float vb_ = xb[h][k] + xr_f[h][k];
                sa_ = fmaf(fmaxf(va, NEG * va), att_f[h][k], sa_);
                sb_ = fmaf(fmaxf(vb_, NEG * vb_), att_f[h][k], sb_);
            }
            pa[h] = red16(sa_);
            pb[h] = red16(sb_);
        }
        if (!vb) { pb[0] = -1e30f; pb[1] = -1e30f; pb[2] = -1e30f; }
#pragma unroll
        for (int h = 0; h < 3; ++h) {
            float mx = fmaxf(pa[h], pb[h]);
            float mn = fmaxf(m[h], mx);
            float c  = __expf(m[h] - mn);
            float wa = __expf(pa[h] - mn);
            float wb = __expf(pb[h] - mn);
            l[h] = fmaf(l[h], c, wa + wb);
            m[h] = mn;
#pragma unroll
            for (int k = 0; k < 8; ++k)
                acc[h][k] = fmaf(acc[h][k], c, fmaf(wa, xa[h][k], wb * xb[h][k]));
        }
    }

    // merge the 4 group states (empty group: m=-1e30, l=0, acc=0 -> adds 0)
#pragma unroll
    for (int o = 16; o <= 32; o <<= 1) {
#pragma unroll
        for (int h = 0; h < 3; ++h) {
            float mo = __shfl_xor(m[h], o);
            float lo = __shfl_xor(l[h], o);
            float mn = fmaxf(m[h], mo);
            float cs = __expf(m[h] - mn);
            float co = __expf(mo - mn);
            l[h] = l[h] * cs + lo * co;
            m[h] = mn;
#pragma unroll
            for (int k = 0; k < 8; ++k)
                acc[h][k] = acc[h][k] * cs + __shfl_xor(acc[h][k], o) * co;
        }
    }

    if (g < 3) {   // group g writes head g (merged state identical in all lanes)
        int h = g;
        float r = 1.f / l[h];
        float bv[8];
        *(float4*)&bv[0] = *(const float4*)&bias[h * 128 + 8 * gl];
        *(float4*)&bv[4] = *(const float4*)&bias[h * 128 + 8 * gl + 4];
        uint4 w;
        w.x = bf16_1(fmaf(acc[h][0], r, bv[0])) | (bf16_1(fmaf(acc[h][1], r, bv[1])) << 16);
        w.y = bf16_1(fmaf(acc[h][2], r, bv[2])) | (bf16_1(fmaf(acc[h][3], r, bv[3])) << 16);
        w.z = bf16_1(fmaf(acc[h][4], r, bv[4])) | (bf16_1(fmaf(acc[h][5], r, bv[5])) << 16);
        w.w = bf16_1(fmaf(acc[h][6], r, bv[6])) | (bf16_1(fmaf(acc[h][7], r, bv[7])) << 16);
        *(uint4*)(outb + (size_t)node * 384 + h * 64 + 4 * gl) = w;
    }
}

// ---------------- BatchNorm (axis=0 over N rows, 128 cols) ----------------

__global__ void k_bn_stats(const float* __restrict__ y, float* __restrict__ stats) {
    int col = threadIdx.x & 127;
    int half = threadIdx.x >> 7;
    float s = 0.f, q = 0.f;
    for (int r = blockIdx.x * 2 + half; r < NN; r += gridDim.x * 2) {
        float v = y[(size_t)r * DD + col];
        s += v; q += v * v;
    }
    __shared__ float sh[256], shq[256];
    sh[threadIdx.x] = s; shq[threadIdx.x] = q;
    __syncthreads();
    if (half == 0) {
        atomicAdd(&stats[col], sh[col] + sh[col + 128]);
        atomicAdd(&stats[128 + col], shq[col] + shq[col + 128]);
    }
}

__global__ void k_bn_apply(float* __restrict__ y, const float* __restrict__ stats,
                           const float* __restrict__ g, const float* __restrict__ be,
                           u16* __restrict__ yb, int wf) {
    int idx = blockIdx.x * 256 + threadIdx.x;
    if (idx < NN * DD) {
        int c = idx & 127;
        const float minv = 1.f / (float)NN;
        float mu = stats[c] * minv;
        float var = stats[128 + c] * minv - mu * mu;
        float sc = g[c] * rsqrtf(var + EPS);
        float sh = be[c] - mu * sc;
        float v = fmaxf(fmaf(y[idx], sc, sh), 0.f);
        if (wf) y[idx] = v;
        if (yb) yb[idx] = (u16)bf16_1(v);
    }
}

// ---------------- launch ----------------

extern "C" void kernel_launch(void* const* d_in, const int* in_sizes, int n_in,
                              void* d_out, int out_size, void* d_ws, size_t ws_size,
                              hipStream_t stream) {
    const float* x    = (const float*)d_in[0];
    const int*   ei   = (const int*)d_in[1];
    const float* Wl1  = (const float*)d_in[2];
    const float* bl1  = (const float*)d_in[3];
    const float* Wr1  = (const float*)d_in[4];
    const float* br1  = (const float*)d_in[5];
    const float* att1 = (const float*)d_in[6];
    const float* bc1  = (const float*)d_in[7];
    const float* g1   = (const float*)d_in[8];
    const float* be1  = (const float*)d_in[9];
    const float* Wl2  = (const float*)d_in[10];
    const float* bl2  = (const float*)d_in[11];
    const float* Wr2  = (const float*)d_in[12];
    const float* br2  = (const float*)d_in[13];
    const float* att2 = (const float*)d_in[14];
    const float* bc2  = (const float*)d_in[15];
    const float* g2   = (const float*)d_in[16];
    const float* be2  = (const float*)d_in[17];
    const float* W1   = (const float*)d_in[18];
    const float* b1   = (const float*)d_in[19];
    const float* W2   = (const float*)d_in[20];
    const float* b2   = (const float*)d_in[21];
    const int* esrc = ei;
    const int* edst = ei + NE;
    float* out = (float*)d_out;

    // ---- workspace layout (all regions 16B-aligned) ----
    float* bufD   = (float*)d_ws;          // mid fp32 [NN,128]      12.8 MB
    float* stats  = bufD + 3200000;        // 512 f (BN1 +0, BN2 +256)
    int* row_ptr  = (int*)(stats + 512);   // 25002
    int* cnt      = row_ptr + 25002;       // 25000
    int* col_src  = cnt + 25000;           // 425000
    int* pad      = col_src + 425000;      // 132
    float* fb1    = (float*)(pad + 132);   // 768 fused bias L1
    float* fb2    = fb1 + 768;             // 768 fused bias L2
    u16* xb       = (u16*)(fb2 + 768);     // x bf16 [NN,128]         6.4 MB
    u16* XL       = xb + 3200000;          // [NN,384] bf16          19.2 MB
    u16* XR       = XL + 9600000;          // [NN,384] bf16 (MUST follow XL: split GEMM)
    u16* bufCat   = XR + 9600000;          // [NN,768] h2|x_in bf16  38.4 MB
    u16* bufDb    = bufCat + 19200000;     // h bf16 [NN,128]         6.4 MB
    u16* WfT1     = bufDb + 3200000;       // [768][128]
    u16* W1T      = WfT1 + 98304;          // [128][384]
    u16* WfT2     = W1T + 49152;           // [768][128]
    u16* W2T      = WfT2 + 98304;          // [128][768]

    // casts + transposes + fused biases + cnt init + stats zero, one kernel
    k_cast_all<<<(CAST_TOTAL + 255) / 256, 256, 0, stream>>>(
        x, Wl1, Wr1, W1, Wl2, Wr2, W2, bl1, br1, bl2, br2,
        xb, WfT1, W1T, WfT2, W2T, fb1, fb2, cnt, stats);

    // CSR (rebuilt every call — identical work each call)
    k_count<<<(NE + 255) / 256, 256, 0, stream>>>(edst, cnt);
    k_scan_all<<<1, 1024, 0, stream>>>(cnt, row_ptr, col_src, cnt);
    k_fill_edges<<<(NE + 255) / 256, 256, 0, stream>>>(esrc, edst, cnt, col_src);

    dim3 blk(256);
    dim3 g768(12, (NN + 127) / 128);
    dim3 g128(2, (NN + 127) / 128);

    // layer 1: [xl|xr] = x @ [Wl1|Wr1] -> XL,XR (split)
    k_gemm_bf<<<g768, blk, 0, stream>>>(xb, WfT1, fb1, nullptr, XL, NN, 768, DD, DD, 1);
    k_gat<<<NN / 4, 256, 0, stream>>>((const u32*)XL, (const u32*)XR, att1, bc1,
                                      row_ptr, col_src, (u32*)bufCat + 192);

    // mid MLP + BN + relu  (A = x_in at bufCat cols 384.., lda=768)
    k_gemm_bf<<<g128, blk, 0, stream>>>(bufCat + 384, W1T, b1, bufD, nullptr, NN, DD, HD, 768, 0);
    k_bn_stats<<<128, 256, 0, stream>>>(bufD, stats);
    k_bn_apply<<<(NN * DD + 255) / 256, 256, 0, stream>>>(bufD, stats, g1, be1, bufDb, 0);

    // layer 2
    k_gemm_bf<<<g768, blk, 0, stream>>>(bufDb, WfT2, fb2, nullptr, XL, NN, 768, DD, DD, 1);
    k_gat<<<NN / 4, 256, 0, stream>>>((const u32*)XL, (const u32*)XR, att2, bc2,
                                      row_ptr, col_src, (u32*)bufCat);

    // final: concat([h2, x_in]) @ W2 + b2 as one K=768 GEMM, then BN+relu
    k_gemm_bf<<<g128, blk, 0, stream>>>(bufCat, W2T, b2, out, nullptr, NN, DD, 768, 768, 0);
    k_bn_stats<<<128, 256, 0, stream>>>(out, stats + 256);
    k_bn_apply<<<(NN * DD + 255) / 256, 256, 0, stream>>>(out, stats + 256, g2, be2, nullptr, 1);
}

// Round 6
// 522.683 us; speedup vs baseline: 1.0571x; 1.0571x over previous
//
#include <hip/hip_runtime.h>
#include <math.h>

#define NN 25000      // nodes
#define NE 400000     // edges
#define DD 128        // hidden dim
#define HD 384        // heads * dim
#define NEG 0.2f
#define EPS 1e-5f

typedef unsigned int u32;
typedef unsigned short u16;
typedef __attribute__((ext_vector_type(8))) short short8;   // 8 bf16 (4 VGPRs)
typedef __attribute__((ext_vector_type(4))) float floatx4;  // MFMA accumulator

// ---- bf16 helpers (RNE) ----
__device__ __forceinline__ u32 bf16_1(float x) {
    u32 u = __float_as_uint(x);
    return (u + 0x7fffu + ((u >> 16) & 1u)) >> 16;
}
__device__ __forceinline__ float blo(u32 u) { return __uint_as_float(u << 16); }
__device__ __forceinline__ float bhi(u32 u) { return __uint_as_float(u & 0xffff0000u); }

__device__ __forceinline__ void up8(uint4 u, float* f) {
    f[0] = blo(u.x); f[1] = bhi(u.x); f[2] = blo(u.y); f[3] = bhi(u.y);
    f[4] = blo(u.z); f[5] = bhi(u.z); f[6] = blo(u.w); f[7] = bhi(u.w);
}

// ---- DPP 16-lane butterfly sum (VALU pipe, no LDS traffic) ----
template<int CTRL>
__device__ __forceinline__ float dpp_add(float x) {
    int t = __builtin_amdgcn_update_dpp(0, __float_as_int(x), CTRL, 0xF, 0xF, true);
    return x + __int_as_float(t);
}
__device__ __forceinline__ float red16(float x) {
    x = dpp_add<0xB1>(x);    // quad_perm xor1
    x = dpp_add<0x4E>(x);    // quad_perm xor2
    x = dpp_add<0x141>(x);   // row_half_mirror (xor4 on quad-uniform)
    x = dpp_add<0x140>(x);   // row_mirror      (xor8 on half-uniform)
    return x;
}

// ---------------- CSR construction (grouped by dst) ----------------

__global__ void k_count(const int* __restrict__ dst, int* __restrict__ cnt) {
    int e = blockIdx.x * 256 + threadIdx.x;
    if (e < NE) atomicAdd(&cnt[dst[e]], 1);
}

__global__ void k_scan1(const int* __restrict__ cnt, int* __restrict__ bsum) {
    __shared__ int sh[256];
    int i = blockIdx.x * 256 + threadIdx.x;
    sh[threadIdx.x] = (i < NN) ? cnt[i] : 0;
    __syncthreads();
    for (int o = 128; o >= 1; o >>= 1) {
        if ((int)threadIdx.x < o) sh[threadIdx.x] += sh[threadIdx.x + o];
        __syncthreads();
    }
    if (threadIdx.x == 0) bsum[blockIdx.x] = sh[0];
}

__global__ void k_scan2(int* __restrict__ bsum, int nblk) {
    __shared__ int sh[128];
    int v = ((int)threadIdx.x < nblk) ? bsum[threadIdx.x] : 0;
    sh[threadIdx.x] = v;
    __syncthreads();
    for (int o = 1; o < 128; o <<= 1) {
        int t = (threadIdx.x >= (unsigned)o) ? sh[threadIdx.x - o] : 0;
        __syncthreads();
        sh[threadIdx.x] += t;
        __syncthreads();
    }
    if ((int)threadIdx.x < nblk) bsum[threadIdx.x] = sh[threadIdx.x];
}

// scan3 + self-loop fill fused
__global__ void k_scan3(const int* __restrict__ cnt, const int* __restrict__ bsum,
                        int* __restrict__ row_ptr, int* __restrict__ col_src,
                        int* __restrict__ cur) {
    __shared__ int sh[256];
    int i = blockIdx.x * 256 + threadIdx.x;
    int v = (i < NN) ? cnt[i] : 0;
    sh[threadIdx.x] = v;
    __syncthreads();
    for (int o = 1; o < 256; o <<= 1) {
        int t = (threadIdx.x >= (unsigned)o) ? sh[threadIdx.x - o] : 0;
        __syncthreads();
        sh[threadIdx.x] += t;
        __syncthreads();
    }
    int base = blockIdx.x ? bsum[blockIdx.x - 1] : 0;
    if (i < NN) {
        int incl = base + sh[threadIdx.x];
        row_ptr[i + 1] = incl;
        int p = incl - v;
        col_src[p] = i;            // self loop first
        cur[i] = p + 1;
    }
    if (i == 0) row_ptr[0] = 0;
}

__global__ void k_fill_edges(const int* __restrict__ src, const int* __restrict__ dst,
                             int* __restrict__ cur, int* __restrict__ col_src) {
    int e = blockIdx.x * 256 + threadIdx.x;
    if (e < NE) { int p = atomicAdd(&cur[dst[e]], 1); col_src[p] = src[e]; }
}

// ---------------- one cast/init kernel for everything ----------------
__global__ void k_cast_all(const float* __restrict__ x,
                           const float* __restrict__ Wl1, const float* __restrict__ Wr1,
                           const float* __restrict__ W1,
                           const float* __restrict__ Wl2, const float* __restrict__ Wr2,
                           const float* __restrict__ W2,
                           const float* __restrict__ bl1, const float* __restrict__ br1,
                           const float* __restrict__ bl2, const float* __restrict__ br2,
                           u16* __restrict__ xb, u16* __restrict__ WfT1,
                           u16* __restrict__ W1T, u16* __restrict__ WfT2,
                           u16* __restrict__ W2T,
                           float* __restrict__ fb1, float* __restrict__ fb2,
                           int* __restrict__ cnt, float* __restrict__ stats) {
    int i = blockIdx.x * 256 + threadIdx.x;
    if (i < 3200000) { xb[i] = (u16)bf16_1(x[i]); return; }
    i -= 3200000;
    if (i < 49152) { int k = i / 384, n = i - k * 384; WfT1[n * 128 + k] = (u16)bf16_1(Wl1[i]); return; }
    i -= 49152;
    if (i < 49152) { int k = i / 384, n = i - k * 384; WfT1[(384 + n) * 128 + k] = (u16)bf16_1(Wr1[i]); return; }
    i -= 49152;
    if (i < 49152) { int k = i / 128, n = i - k * 128; W1T[n * 384 + k] = (u16)bf16_1(W1[i]); return; }
    i -= 49152;
    if (i < 49152) { int k = i / 384, n = i - k * 384; WfT2[n * 128 + k] = (u16)bf16_1(Wl2[i]); return; }
    i -= 49152;
    if (i < 49152) { int k = i / 384, n = i - k * 384; WfT2[(384 + n) * 128 + k] = (u16)bf16_1(Wr2[i]); return; }
    i -= 49152;
    if (i < 98304) { int k = i / 128, n = i - k * 128; W2T[n * 768 + k] = (u16)bf16_1(W2[i]); return; }
    i -= 98304;
    if (i < 768) { fb1[i] = (i < 384) ? bl1[i] : br1[i - 384]; return; }
    i -= 768;
    if (i < 768) { fb2[i] = (i < 384) ? bl2[i] : br2[i - 384]; return; }
    i -= 768;
    if (i < 25000) { cnt[i] = 1; return; }   // self loop
    i -= 25000;
    if (i < 512) stats[i] = 0.f;
}
#define CAST_TOTAL (3200000 + 5 * 49152 + 98304 + 1536 + 25000 + 512)

// ---------------- bf16 MFMA GEMM: C[M,N] = A[M,K] @ BT[N,K]^T (+bias) ----------------
// BM=128, BN=128, BK=64, 256 threads. global_load_lds(16B) staging with
// XOR-swizzled source addressing (LDS dest stays lane-contiguous as HW needs).
// split!=0: Cb is XL base; col>=384 goes to XL+NN*384 (XR), row stride 384.
__global__ __launch_bounds__(256) void k_gemm_bf(
        const u16* __restrict__ A, const u16* __restrict__ BT,
        const float* __restrict__ bias,
        float* __restrict__ Cf, u16* __restrict__ Cb,
        int M, int N, int K, int lda, int split) {
    __shared__ short sA[128 * 64];
    __shared__ short sB[128 * 64];
    int tid = threadIdx.x;
    int wv = tid >> 6, lane = tid & 63;
    int quad = lane >> 4, m16 = lane & 15;
    int sw = m16 & 7;
    int mb = blockIdx.y * 128, nb = blockIdx.x * 128;

    floatx4 acc[2][8];
#pragma unroll
    for (int mf = 0; mf < 2; ++mf)
#pragma unroll
        for (int nf = 0; nf < 8; ++nf)
#pragma unroll
            for (int r = 0; r < 4; ++r) acc[mf][nf][r] = 0.f;

    for (int k0 = 0; k0 < K; k0 += 64) {
#pragma unroll
        for (int j = 0; j < 4; ++j) {
            int L = (wv * 4 + j) * 64 + lane;
            int r = L >> 3, c8 = (L & 7) ^ (r & 7);
            int gr = mb + r; gr = gr < M ? gr : M - 1;
            __builtin_amdgcn_global_load_lds(
                (const __attribute__((address_space(1))) void*)(A + (size_t)gr * lda + k0 + c8 * 8),
                (__attribute__((address_space(3))) void*)(sA + (size_t)(wv * 4 + j) * 512),
                16, 0, 0);
        }
#pragma unroll
        for (int j = 0; j < 4; ++j) {
            int L = (wv * 4 + j) * 64 + lane;
            int r = L >> 3, c8 = (L & 7) ^ (r & 7);
            __builtin_amdgcn_global_load_lds(
                (const __attribute__((address_space(1))) void*)(BT + (size_t)(nb + r) * K + k0 + c8 * 8),
                (__attribute__((address_space(3))) void*)(sB + (size_t)(wv * 4 + j) * 512),
                16, 0, 0);
        }
        __syncthreads();
#pragma unroll
        for (int ks = 0; ks < 2; ++ks) {
            int t = (ks * 4 + quad) ^ sw;
            const short* pa = sA + t * 8;
            const short* pb = sB + t * 8;
            short8 a0 = *(const short8*)(pa + (wv * 32 + m16) * 64);
            short8 a1 = *(const short8*)(pa + (wv * 32 + 16 + m16) * 64);
#pragma unroll
            for (int nf = 0; nf < 8; ++nf) {
                short8 b = *(const short8*)(pb + (nf * 16 + m16) * 64);
                acc[0][nf] = __builtin_amdgcn_mfma_f32_16x16x32_bf16(a0, b, acc[0][nf], 0, 0, 0);
                acc[1][nf] = __builtin_amdgcn_mfma_f32_16x16x32_bf16(a1, b, acc[1][nf], 0, 0, 0);
            }
        }
        __syncthreads();
    }
    // epilogue: C/D layout col=lane&15, row=quad*4+reg
#pragma unroll
    for (int mf = 0; mf < 2; ++mf) {
        int rbase = mb + wv * 32 + mf * 16 + quad * 4;
#pragma unroll
        for (int nf = 0; nf < 8; ++nf) {
            int col = nb + nf * 16 + m16;
            float bv = bias ? bias[col] : 0.f;
            u16* cb = Cb;
            int c2 = col, ldcb = N;
            if (split) {
                ldcb = 384;
                if (col >= 384) { cb = Cb + (size_t)NN * 384; c2 = col - 384; }
            }
#pragma unroll
            for (int r = 0; r < 4; ++r) {
                int row = rbase + r;
                if (row < M) {
                    float v = acc[mf][nf][r] + bv;
                    if (Cf) Cf[(size_t)row * N + col] = v;
                    if (Cb) cb[(size_t)row * ldcb + c2] = (u16)bf16_1(v);
                }
            }
        }
    }
}

// ---------------- GATv2 aggregate ----------------
// One wave per dst node; 4 groups of 16 lanes; group g handles edges
// e0+g, e0+g+4, ... with depth-1 prefetch. Lane gl holds dims [8gl,8gl+8)
// of each head. DPP butterfly for the 16-lane score reduce (VALU pipe).
// Branchless online-softmax update. Flash-merge of 4 group states at end
// (shfl_xor 16,32) with -1e30 empty-group sentinel.
__global__ __launch_bounds__(256) void k_gat(const u32* __restrict__ XL,
                                             const u32* __restrict__ XR,
                                             const float* __restrict__ att,
                                             const float* __restrict__ bias,
                                             const int* __restrict__ row_ptr,
                                             const int* __restrict__ col_src,
                                             u32* __restrict__ outb) {
    int node = blockIdx.x * 4 + (threadIdx.x >> 6);
    int lane = threadIdx.x & 63;
    int g = lane >> 4, gl = lane & 15;

    const u32* xrp = XR + (size_t)node * 192 + 4 * gl;
    float xr_f[3][8], att_f[3][8], acc[3][8], m[3], l[3];
#pragma unroll
    for (int h = 0; h < 3; ++h) {
        up8(*(const uint4*)(xrp + h * 64), xr_f[h]);
        *(float4*)&att_f[h][0] = *(const float4*)&att[h * 128 + 8 * gl];
        *(float4*)&att_f[h][4] = *(const float4*)&att[h * 128 + 8 * gl + 4];
#pragma unroll
        for (int k = 0; k < 8; ++k) acc[h][k] = 0.f;
        m[h] = -1e30f; l[h] = 0.f;
    }

    int e0 = row_ptr[node];
    int cntE = row_ptr[node + 1] - e0;
    int elast = e0 + cntE - 1;

    // prefetch first edge (clamped; groups with t>=cntE never use it)
    int ea = e0 + g; ea = ea < elast ? ea : elast;
    int s = col_src[ea];
    const u32* xp = XL + (size_t)s * 192 + 4 * gl;
    uint4 u0 = *(const uint4*)xp, u1 = *(const uint4*)(xp + 64), u2 = *(const uint4*)(xp + 128);

    for (int t = g; t < cntE; t += 4) {
        float xv[3][8];
        up8(u0, xv[0]); up8(u1, xv[1]); up8(u2, xv[2]);
        int tn = t + 4;
        ea = e0 + tn; ea = ea < elast ? ea : elast;
        s = col_src[ea];
        xp = XL + (size_t)s * 192 + 4 * gl;
        u0 = *(const uint4*)xp; u1 = *(const uint4*)(xp + 64); u2 = *(const uint4*)(xp + 128);

        float p[3];
#pragma unroll
        for (int h = 0; h < 3; ++h) {
            float ph = 0.f;
#pragma unroll
            for (int k = 0; k < 8; ++k) {
                float v = xv[h][k] + xr_f[h][k];
                ph = fmaf(fmaxf(v, NEG * v), att_f[h][k], ph);
            }
            p[h] = red16(ph);
        }
#pragma unroll
        for (int h = 0; h < 3; ++h) {
            float mn = fmaxf(m[h], p[h]);
            float c = __expf(m[h] - mn), w = __expf(p[h] - mn);
            l[h] = fmaf(l[h], c, w);
            m[h] = mn;
#pragma unroll
            for (int k = 0; k < 8; ++k)
                acc[h][k] = fmaf(acc[h][k], c, w * xv[h][k]);
        }
    }

    // merge the 4 group states (empty group: m=-1e30, l=0, acc=0 -> adds 0)
#pragma unroll
    for (int o = 16; o <= 32; o <<= 1) {
#pragma unroll
        for (int h = 0; h < 3; ++h) {
            float mo = __shfl_xor(m[h], o);
            float lo = __shfl_xor(l[h], o);
            float mn = fmaxf(m[h], mo);
            float cs = __expf(m[h] - mn);
            float co = __expf(mo - mn);
            l[h] = l[h] * cs + lo * co;
            m[h] = mn;
#pragma unroll
            for (int k = 0; k < 8; ++k)
                acc[h][k] = acc[h][k] * cs + __shfl_xor(acc[h][k], o) * co;
        }
    }

    if (g < 3) {   // group g writes head g (merged state identical in all lanes)
        int h = g;
        float r = 1.f / l[h];
        float bv[8];
        *(float4*)&bv[0] = *(const float4*)&bias[h * 128 + 8 * gl];
        *(float4*)&bv[4] = *(const float4*)&bias[h * 128 + 8 * gl + 4];
        uint4 w;
        w.x = bf16_1(fmaf(acc[h][0], r, bv[0])) | (bf16_1(fmaf(acc[h][1], r, bv[1])) << 16);
        w.y = bf16_1(fmaf(acc[h][2], r, bv[2])) | (bf16_1(fmaf(acc[h][3], r, bv[3])) << 16);
        w.z = bf16_1(fmaf(acc[h][4], r, bv[4])) | (bf16_1(fmaf(acc[h][5], r, bv[5])) << 16);
        w.w = bf16_1(fmaf(acc[h][6], r, bv[6])) | (bf16_1(fmaf(acc[h][7], r, bv[7])) << 16);
        *(uint4*)(outb + (size_t)node * 384 + h * 64 + 4 * gl) = w;
    }
}

// ---------------- BatchNorm (axis=0 over N rows, 128 cols) ----------------

__global__ void k_bn_stats(const float* __restrict__ y, float* __restrict__ stats) {
    int col = threadIdx.x & 127;
    int half = threadIdx.x >> 7;
    float s = 0.f, q = 0.f;
    for (int r = blockIdx.x * 2 + half; r < NN; r += gridDim.x * 2) {
        float v = y[(size_t)r * DD + col];
        s += v; q += v * v;
    }
    __shared__ float sh[256], shq[256];
    sh[threadIdx.x] = s; shq[threadIdx.x] = q;
    __syncthreads();
    if (half == 0) {
        atomicAdd(&stats[col], sh[col] + sh[col + 128]);
        atomicAdd(&stats[128 + col], shq[col] + shq[col + 128]);
    }
}

__global__ void k_bn_apply(float* __restrict__ y, const float* __restrict__ stats,
                           const float* __restrict__ g, const float* __restrict__ be,
                           u16* __restrict__ yb, int wf) {
    int idx = blockIdx.x * 256 + threadIdx.x;
    if (idx < NN * DD) {
        int c = idx & 127;
        const float minv = 1.f / (float)NN;
        float mu = stats[c] * minv;
        float var = stats[128 + c] * minv - mu * mu;
        float sc = g[c] * rsqrtf(var + EPS);
        float sh = be[c] - mu * sc;
        float v = fmaxf(fmaf(y[idx], sc, sh), 0.f);
        if (wf) y[idx] = v;
        if (yb) yb[idx] = (u16)bf16_1(v);
    }
}

// ---------------- launch ----------------

extern "C" void kernel_launch(void* const* d_in, const int* in_sizes, int n_in,
                              void* d_out, int out_size, void* d_ws, size_t ws_size,
                              hipStream_t stream) {
    const float* x    = (const float*)d_in[0];
    const int*   ei   = (const int*)d_in[1];
    const float* Wl1  = (const float*)d_in[2];
    const float* bl1  = (const float*)d_in[3];
    const float* Wr1  = (const float*)d_in[4];
    const float* br1  = (const float*)d_in[5];
    const float* att1 = (const float*)d_in[6];
    const float* bc1  = (const float*)d_in[7];
    const float* g1   = (const float*)d_in[8];
    const float* be1  = (const float*)d_in[9];
    const float* Wl2  = (const float*)d_in[10];
    const float* bl2  = (const float*)d_in[11];
    const float* Wr2  = (const float*)d_in[12];
    const float* br2  = (const float*)d_in[13];
    const float* att2 = (const float*)d_in[14];
    const float* bc2  = (const float*)d_in[15];
    const float* g2   = (const float*)d_in[16];
    const float* be2  = (const float*)d_in[17];
    const float* W1   = (const float*)d_in[18];
    const float* b1   = (const float*)d_in[19];
    const float* W2   = (const float*)d_in[20];
    const float* b2   = (const float*)d_in[21];
    const int* esrc = ei;
    const int* edst = ei + NE;
    float* out = (float*)d_out;

    // ---- workspace layout (all regions 16B-aligned) ----
    float* bufD   = (float*)d_ws;          // mid fp32 [NN,128]      12.8 MB
    float* stats  = bufD + 3200000;        // 512 f (BN1 +0, BN2 +256)
    int* row_ptr  = (int*)(stats + 512);   // 25002
    int* cnt      = row_ptr + 25002;       // 25000
    int* col_src  = cnt + 25000;           // 425000
    int* bsum     = col_src + 425000;      // 132 (pad)
    float* fb1    = (float*)(bsum + 132);  // 768 fused bias L1
    float* fb2    = fb1 + 768;             // 768 fused bias L2
    u16* xb       = (u16*)(fb2 + 768);     // x bf16 [NN,128]         6.4 MB
    u16* XL       = xb + 3200000;          // [NN,384] bf16          19.2 MB
    u16* XR       = XL + 9600000;          // [NN,384] bf16 (MUST follow XL: split GEMM)
    u16* bufCat   = XR + 9600000;          // [NN,768] h2|x_in bf16  38.4 MB
    u16* bufDb    = bufCat + 19200000;     // h bf16 [NN,128]         6.4 MB
    u16* WfT1     = bufDb + 3200000;       // [768][128]
    u16* W1T      = WfT1 + 98304;          // [128][384]
    u16* WfT2     = W1T + 49152;           // [768][128]
    u16* W2T      = WfT2 + 98304;          // [128][768]

    // casts + transposes + fused biases + cnt init + stats zero, one kernel
    k_cast_all<<<(CAST_TOTAL + 255) / 256, 256, 0, stream>>>(
        x, Wl1, Wr1, W1, Wl2, Wr2, W2, bl1, br1, bl2, br2,
        xb, WfT1, W1T, WfT2, W2T, fb1, fb2, cnt, stats);

    // CSR (rebuilt every call — identical work each call)
    k_count<<<(NE + 255) / 256, 256, 0, stream>>>(edst, cnt);
    k_scan1<<<98, 256, 0, stream>>>(cnt, bsum);
    k_scan2<<<1, 128, 0, stream>>>(bsum, 98);
    k_scan3<<<98, 256, 0, stream>>>(cnt, bsum, row_ptr, col_src, cnt);
    k_fill_edges<<<(NE + 255) / 256, 256, 0, stream>>>(esrc, edst, cnt, col_src);

    dim3 blk(256);
    dim3 g768(6, (NN + 127) / 128);   // BN=128
    dim3 g128(1, (NN + 127) / 128);

    // layer 1: [xl|xr] = x @ [Wl1|Wr1] -> XL,XR (split)
    k_gemm_bf<<<g768, blk, 0, stream>>>(xb, WfT1, fb1, nullptr, XL, NN, 768, DD, DD, 1);
    k_gat<<<NN / 4, 256, 0, stream>>>((const u32*)XL, (const u32*)XR, att1, bc1,
                                      row_ptr, col_src, (u32*)bufCat + 192);

    // mid MLP + BN + relu  (A = x_in at bufCat cols 384.., lda=768)
    k_gemm_bf<<<g128, blk, 0, stream>>>(bufCat + 384, W1T, b1, bufD, nullptr, NN, DD, HD, 768, 0);
    k_bn_stats<<<128, 256, 0, stream>>>(bufD, stats);
    k_bn_apply<<<(NN * DD + 255) / 256, 256, 0, stream>>>(bufD, stats, g1, be1, bufDb, 0);

    // layer 2
    k_gemm_bf<<<g768, blk, 0, stream>>>(bufDb, WfT2, fb2, nullptr, XL, NN, 768, DD, DD, 1);
    k_gat<<<NN / 4, 256, 0, stream>>>((const u32*)XL, (const u32*)XR, att2, bc2,
                                      row_ptr, col_src, (u32*)bufCat);

    // final: concat([h2, x_in]) @ W2 + b2 as one K=768 GEMM, then BN+relu
    k_gemm_bf<<<g128, blk, 0, stream>>>(bufCat, W2T, b2, out, nullptr, NN, DD, 768, 768, 0);
    k_bn_stats<<<128, 256, 0, stream>>>(out, stats + 256);
    k_bn_apply<<<(NN * DD + 255) / 256, 256, 0, stream>>>(out, stats + 256, g2, be2, nullptr, 1);
}

// Round 7
// 511.083 us; speedup vs baseline: 1.0811x; 1.0227x over previous
//
#include <hip/hip_runtime.h>
#include <math.h>

#define NN 25000      // nodes
#define NE 400000     // edges
#define DD 128        // hidden dim
#define HD 384        // heads * dim
#define NEG 0.2f
#define EPS 1e-5f

typedef unsigned int u32;
typedef unsigned short u16;
typedef __attribute__((ext_vector_type(8))) short short8;   // 8 bf16 (4 VGPRs)
typedef __attribute__((ext_vector_type(4))) float floatx4;  // MFMA accumulator

// ---- bf16 helpers (RNE) ----
__device__ __forceinline__ u32 bf16_1(float x) {
    u32 u = __float_as_uint(x);
    return (u + 0x7fffu + ((u >> 16) & 1u)) >> 16;
}
__device__ __forceinline__ float blo(u32 u) { return __uint_as_float(u << 16); }
__device__ __forceinline__ float bhi(u32 u) { return __uint_as_float(u & 0xffff0000u); }

__device__ __forceinline__ void up8(uint4 u, float* f) {
    f[0] = blo(u.x); f[1] = bhi(u.x); f[2] = blo(u.y); f[3] = bhi(u.y);
    f[4] = blo(u.z); f[5] = bhi(u.z); f[6] = blo(u.w); f[7] = bhi(u.w);
}

// ---------------- CSR construction (grouped by dst) ----------------

__global__ void k_count(const int* __restrict__ dst, int* __restrict__ cnt) {
    int e = blockIdx.x * 256 + threadIdx.x;
    if (e < NE) atomicAdd(&cnt[dst[e]], 1);
}

__global__ void k_scan1(const int* __restrict__ cnt, int* __restrict__ bsum) {
    __shared__ int sh[256];
    int i = blockIdx.x * 256 + threadIdx.x;
    sh[threadIdx.x] = (i < NN) ? cnt[i] : 0;
    __syncthreads();
    for (int o = 128; o >= 1; o >>= 1) {
        if ((int)threadIdx.x < o) sh[threadIdx.x] += sh[threadIdx.x + o];
        __syncthreads();
    }
    if (threadIdx.x == 0) bsum[blockIdx.x] = sh[0];
}

__global__ void k_scan2(int* __restrict__ bsum, int nblk) {
    __shared__ int sh[128];
    int v = ((int)threadIdx.x < nblk) ? bsum[threadIdx.x] : 0;
    sh[threadIdx.x] = v;
    __syncthreads();
    for (int o = 1; o < 128; o <<= 1) {
        int t = (threadIdx.x >= (unsigned)o) ? sh[threadIdx.x - o] : 0;
        __syncthreads();
        sh[threadIdx.x] += t;
        __syncthreads();
    }
    if ((int)threadIdx.x < nblk) bsum[threadIdx.x] = sh[threadIdx.x];
}

// scan3 + self-loop fill fused
__global__ void k_scan3(const int* __restrict__ cnt, const int* __restrict__ bsum,
                        int* __restrict__ row_ptr, int* __restrict__ col_src,
                        int* __restrict__ cur) {
    __shared__ int sh[256];
    int i = blockIdx.x * 256 + threadIdx.x;
    int v = (i < NN) ? cnt[i] : 0;
    sh[threadIdx.x] = v;
    __syncthreads();
    for (int o = 1; o < 256; o <<= 1) {
        int t = (threadIdx.x >= (unsigned)o) ? sh[threadIdx.x - o] : 0;
        __syncthreads();
        sh[threadIdx.x] += t;
        __syncthreads();
    }
    int base = blockIdx.x ? bsum[blockIdx.x - 1] : 0;
    if (i < NN) {
        int incl = base + sh[threadIdx.x];
        row_ptr[i + 1] = incl;
        int p = incl - v;
        col_src[p] = i;            // self loop first
        cur[i] = p + 1;
    }
    if (i == 0) row_ptr[0] = 0;
}

__global__ void k_fill_edges(const int* __restrict__ src, const int* __restrict__ dst,
                             int* __restrict__ cur, int* __restrict__ col_src) {
    int e = blockIdx.x * 256 + threadIdx.x;
    if (e < NE) { int p = atomicAdd(&cur[dst[e]], 1); col_src[p] = src[e]; }
}

// ---------------- one cast/init kernel for everything ----------------
__global__ void k_cast_all(const float* __restrict__ x,
                           const float* __restrict__ Wl1, const float* __restrict__ Wr1,
                           const float* __restrict__ W1,
                           const float* __restrict__ Wl2, const float* __restrict__ Wr2,
                           const float* __restrict__ W2,
                           const float* __restrict__ bl1, const float* __restrict__ br1,
                           const float* __restrict__ bl2, const float* __restrict__ br2,
                           u16* __restrict__ xb, u16* __restrict__ WfT1,
                           u16* __restrict__ W1T, u16* __restrict__ WfT2,
                           u16* __restrict__ W2T,
                           float* __restrict__ fb1, float* __restrict__ fb2,
                           int* __restrict__ cnt, float* __restrict__ stats) {
    int i = blockIdx.x * 256 + threadIdx.x;
    if (i < 3200000) { xb[i] = (u16)bf16_1(x[i]); return; }
    i -= 3200000;
    if (i < 49152) { int k = i / 384, n = i - k * 384; WfT1[n * 128 + k] = (u16)bf16_1(Wl1[i]); return; }
    i -= 49152;
    if (i < 49152) { int k = i / 384, n = i - k * 384; WfT1[(384 + n) * 128 + k] = (u16)bf16_1(Wr1[i]); return; }
    i -= 49152;
    if (i < 49152) { int k = i / 128, n = i - k * 128; W1T[n * 384 + k] = (u16)bf16_1(W1[i]); return; }
    i -= 49152;
    if (i < 49152) { int k = i / 384, n = i - k * 384; WfT2[n * 128 + k] = (u16)bf16_1(Wl2[i]); return; }
    i -= 49152;
    if (i < 49152) { int k = i / 384, n = i - k * 384; WfT2[(384 + n) * 128 + k] = (u16)bf16_1(Wr2[i]); return; }
    i -= 49152;
    if (i < 98304) { int k = i / 128, n = i - k * 128; W2T[n * 768 + k] = (u16)bf16_1(W2[i]); return; }
    i -= 98304;
    if (i < 768) { fb1[i] = (i < 384) ? bl1[i] : br1[i - 384]; return; }
    i -= 768;
    if (i < 768) { fb2[i] = (i < 384) ? bl2[i] : br2[i - 384]; return; }
    i -= 768;
    if (i < 25000) { cnt[i] = 1; return; }   // self loop
    i -= 25000;
    if (i < 512) stats[i] = 0.f;
}
#define CAST_TOTAL (3200000 + 5 * 49152 + 98304 + 1536 + 25000 + 512)

// ---------------- bf16 MFMA GEMM: C[M,N] = A[M,K] @ BT[N,K]^T (+bias) ----------------
// BM=128, BN=NF*16, BK=64, 256 threads. global_load_lds(16B) staging with
// XOR-swizzled source addressing. SPLIT: Cb is XL base; col>=384 -> XL+NN*384.
template<int NF, int SPLIT>
__global__ __launch_bounds__(256) void k_gemm_bf(
        const u16* __restrict__ A, const u16* __restrict__ BT,
        const float* __restrict__ bias,
        float* __restrict__ Cf, u16* __restrict__ Cb,
        int M, int N, int K, int lda) {
    __shared__ short sA[128 * 64];
    __shared__ short sB[NF * 16 * 64];
    int tid = threadIdx.x;
    int wv = tid >> 6, lane = tid & 63;
    int quad = lane >> 4, m16 = lane & 15;
    int sw = m16 & 7;
    int mb = blockIdx.y * 128, nb = blockIdx.x * (NF * 16);

    floatx4 acc[2][NF];
#pragma unroll
    for (int mf = 0; mf < 2; ++mf)
#pragma unroll
        for (int nf = 0; nf < NF; ++nf)
#pragma unroll
            for (int r = 0; r < 4; ++r) acc[mf][nf][r] = 0.f;

    for (int k0 = 0; k0 < K; k0 += 64) {
#pragma unroll
        for (int j = 0; j < 4; ++j) {
            int L = (wv * 4 + j) * 64 + lane;
            int r = L >> 3, c8 = (L & 7) ^ (r & 7);
            int gr = mb + r; gr = gr < M ? gr : M - 1;
            __builtin_amdgcn_global_load_lds(
                (const __attribute__((address_space(1))) void*)(A + (size_t)gr * lda + k0 + c8 * 8),
                (__attribute__((address_space(3))) void*)(sA + (size_t)(wv * 4 + j) * 512),
                16, 0, 0);
        }
#pragma unroll
        for (int j = 0; j < NF / 2; ++j) {
            int L = (wv * (NF / 2) + j) * 64 + lane;
            int r = L >> 3, c8 = (L & 7) ^ (r & 7);
            __builtin_amdgcn_global_load_lds(
                (const __attribute__((address_space(1))) void*)(BT + (size_t)(nb + r) * K + k0 + c8 * 8),
                (__attribute__((address_space(3))) void*)(sB + (size_t)(wv * (NF / 2) + j) * 512),
                16, 0, 0);
        }
        __syncthreads();
#pragma unroll
        for (int ks = 0; ks < 2; ++ks) {
            int t = (ks * 4 + quad) ^ sw;
            const short* pa = sA + t * 8;
            const short* pb = sB + t * 8;
            short8 a0 = *(const short8*)(pa + (wv * 32 + m16) * 64);
            short8 a1 = *(const short8*)(pa + (wv * 32 + 16 + m16) * 64);
#pragma unroll
            for (int nf = 0; nf < NF; ++nf) {
                short8 b = *(const short8*)(pb + (nf * 16 + m16) * 64);
                acc[0][nf] = __builtin_amdgcn_mfma_f32_16x16x32_bf16(a0, b, acc[0][nf], 0, 0, 0);
                acc[1][nf] = __builtin_amdgcn_mfma_f32_16x16x32_bf16(a1, b, acc[1][nf], 0, 0, 0);
            }
        }
        __syncthreads();
    }
    // epilogue: C/D layout col=lane&15, row=quad*4+reg
#pragma unroll
    for (int mf = 0; mf < 2; ++mf) {
        int rbase = mb + wv * 32 + mf * 16 + quad * 4;
#pragma unroll
        for (int nf = 0; nf < NF; ++nf) {
            int col = nb + nf * 16 + m16;
            float bv = bias ? bias[col] : 0.f;
            u16* cb = Cb;
            int c2 = col, ldcb = N;
            if (SPLIT) {
                ldcb = 384;
                if (col >= 384) { cb = Cb + (size_t)NN * 384; c2 = col - 384; }
            }
#pragma unroll
            for (int r = 0; r < 4; ++r) {
                int row = rbase + r;
                if (row < M) {
                    float v = acc[mf][nf][r] + bv;
                    if (Cf) Cf[(size_t)row * N + col] = v;
                    if (Cb) cb[(size_t)row * ldcb + c2] = (u16)bf16_1(v);
                }
            }
        }
    }
}

// ---------------- GATv2 aggregate ----------------
// One wave per dst node (node range [nbase, nbase+count)); 4 groups of 16
// lanes; group g handles edges e0+g, e0+g+4, ... with guarded depth-1
// prefetch. shfl_xor butterfly (ds_bpermute -> idle LDS pipe) for the score
// reduce. Branchless online-softmax. Flash-merge of 4 group states at end.
__global__ __launch_bounds__(256) void k_gat(const u32* __restrict__ XL,
                                             const u32* __restrict__ XR,
                                             const float* __restrict__ att,
                                             const float* __restrict__ bias,
                                             const int* __restrict__ row_ptr,
                                             const int* __restrict__ col_src,
                                             u32* __restrict__ outb, int nbase) {
    int node = nbase + blockIdx.x * 4 + (threadIdx.x >> 6);
    int lane = threadIdx.x & 63;
    int g = lane >> 4, gl = lane & 15;

    const u32* xrp = XR + (size_t)node * 192 + 4 * gl;
    float xr_f[3][8], att_f[3][8], acc[3][8], m[3], l[3];
#pragma unroll
    for (int h = 0; h < 3; ++h) {
        up8(*(const uint4*)(xrp + h * 64), xr_f[h]);
        *(float4*)&att_f[h][0] = *(const float4*)&att[h * 128 + 8 * gl];
        *(float4*)&att_f[h][4] = *(const float4*)&att[h * 128 + 8 * gl + 4];
#pragma unroll
        for (int k = 0; k < 8; ++k) acc[h][k] = 0.f;
        m[h] = -1e30f; l[h] = 0.f;
    }

    int e0 = row_ptr[node];
    int cntE = row_ptr[node + 1] - e0;

    uint4 u0 = {}, u1 = {}, u2 = {};
    if (g < cntE) {
        int s = col_src[e0 + g];
        const u32* xp = XL + (size_t)s * 192 + 4 * gl;
        u0 = *(const uint4*)xp; u1 = *(const uint4*)(xp + 64); u2 = *(const uint4*)(xp + 128);
    }
    for (int t = g; t < cntE; t += 4) {
        float xv[3][8];
        up8(u0, xv[0]); up8(u1, xv[1]); up8(u2, xv[2]);
        int tn = t + 4;
        if (tn < cntE) {   // guarded depth-1 prefetch
            int s = col_src[e0 + tn];
            const u32* xp = XL + (size_t)s * 192 + 4 * gl;
            u0 = *(const uint4*)xp; u1 = *(const uint4*)(xp + 64); u2 = *(const uint4*)(xp + 128);
        }
        float p[3];
#pragma unroll
        for (int h = 0; h < 3; ++h) {
            float ph = 0.f;
#pragma unroll
            for (int k = 0; k < 8; ++k) {
                float v = xv[h][k] + xr_f[h][k];
                ph = fmaf(fmaxf(v, NEG * v), att_f[h][k], ph);
            }
            p[h] = ph;
        }
#pragma unroll
        for (int o = 1; o <= 8; o <<= 1) {
            p[0] += __shfl_xor(p[0], o);
            p[1] += __shfl_xor(p[1], o);
            p[2] += __shfl_xor(p[2], o);
        }
#pragma unroll
        for (int h = 0; h < 3; ++h) {
            float mn = fmaxf(m[h], p[h]);
            float c = __expf(m[h] - mn), w = __expf(p[h] - mn);
            l[h] = fmaf(l[h], c, w);
            m[h] = mn;
#pragma unroll
            for (int k = 0; k < 8; ++k)
                acc[h][k] = fmaf(acc[h][k], c, w * xv[h][k]);
        }
    }

    // merge the 4 group states (empty group: m=-1e30, l=0, acc=0 -> adds 0)
#pragma unroll
    for (int o = 16; o <= 32; o <<= 1) {
#pragma unroll
        for (int h = 0; h < 3; ++h) {
            float mo = __shfl_xor(m[h], o);
            float lo = __shfl_xor(l[h], o);
            float mn = fmaxf(m[h], mo);
            float cs = __expf(m[h] - mn);
            float co = __expf(mo - mn);
            l[h] = l[h] * cs + lo * co;
            m[h] = mn;
#pragma unroll
            for (int k = 0; k < 8; ++k)
                acc[h][k] = acc[h][k] * cs + __shfl_xor(acc[h][k], o) * co;
        }
    }

    if (g < 3) {   // group g writes head g (merged state identical in all lanes)
        int h = g;
        float r = 1.f / l[h];
        float bv[8];
        *(float4*)&bv[0] = *(const float4*)&bias[h * 128 + 8 * gl];
        *(float4*)&bv[4] = *(const float4*)&bias[h * 128 + 8 * gl + 4];
        uint4 w;
        w.x = bf16_1(fmaf(acc[h][0], r, bv[0])) | (bf16_1(fmaf(acc[h][1], r, bv[1])) << 16);
        w.y = bf16_1(fmaf(acc[h][2], r, bv[2])) | (bf16_1(fmaf(acc[h][3], r, bv[3])) << 16);
        w.z = bf16_1(fmaf(acc[h][4], r, bv[4])) | (bf16_1(fmaf(acc[h][5], r, bv[5])) << 16);
        w.w = bf16_1(fmaf(acc[h][6], r, bv[6])) | (bf16_1(fmaf(acc[h][7], r, bv[7])) << 16);
        *(uint4*)(outb + (size_t)node * 384 + h * 64 + 4 * gl) = w;
    }
}

// ---------------- BatchNorm (axis=0 over N rows, 128 cols) ----------------

__global__ void k_bn_stats(const float* __restrict__ y, float* __restrict__ stats) {
    int col = threadIdx.x & 127;
    int half = threadIdx.x >> 7;
    float s = 0.f, q = 0.f;
    for (int r = blockIdx.x * 2 + half; r < NN; r += gridDim.x * 2) {
        float v = y[(size_t)r * DD + col];
        s += v; q += v * v;
    }
    __shared__ float sh[256], shq[256];
    sh[threadIdx.x] = s; shq[threadIdx.x] = q;
    __syncthreads();
    if (half == 0) {
        atomicAdd(&stats[col], sh[col] + sh[col + 128]);
        atomicAdd(&stats[128 + col], shq[col] + shq[col + 128]);
    }
}

__global__ void k_bn_apply(float* __restrict__ y, const float* __restrict__ stats,
                           const float* __restrict__ g, const float* __restrict__ be,
                           u16* __restrict__ yb, int wf) {
    int idx = blockIdx.x * 256 + threadIdx.x;
    if (idx < NN * DD) {
        int c = idx & 127;
        const float minv = 1.f / (float)NN;
        float mu = stats[c] * minv;
        float var = stats[128 + c] * minv - mu * mu;
        float sc = g[c] * rsqrtf(var + EPS);
        float sh = be[c] - mu * sc;
        float v = fmaxf(fmaf(y[idx], sc, sh), 0.f);
        if (wf) y[idx] = v;
        if (yb) yb[idx] = (u16)bf16_1(v);
    }
}

// ---------------- launch ----------------

extern "C" void kernel_launch(void* const* d_in, const int* in_sizes, int n_in,
                              void* d_out, int out_size, void* d_ws, size_t ws_size,
                              hipStream_t stream) {
    const float* x    = (const float*)d_in[0];
    const int*   ei   = (const int*)d_in[1];
    const float* Wl1  = (const float*)d_in[2];
    const float* bl1  = (const float*)d_in[3];
    const float* Wr1  = (const float*)d_in[4];
    const float* br1  = (const float*)d_in[5];
    const float* att1 = (const float*)d_in[6];
    const float* bc1  = (const float*)d_in[7];
    const float* g1   = (const float*)d_in[8];
    const float* be1  = (const float*)d_in[9];
    const float* Wl2  = (const float*)d_in[10];
    const float* bl2  = (const float*)d_in[11];
    const float* Wr2  = (const float*)d_in[12];
    const float* br2  = (const float*)d_in[13];
    const float* att2 = (const float*)d_in[14];
    const float* bc2  = (const float*)d_in[15];
    const float* g2   = (const float*)d_in[16];
    const float* be2  = (const float*)d_in[17];
    const float* W1   = (const float*)d_in[18];
    const float* b1   = (const float*)d_in[19];
    const float* W2   = (const float*)d_in[20];
    const float* b2   = (const float*)d_in[21];
    const int* esrc = ei;
    const int* edst = ei + NE;
    float* out = (float*)d_out;

    // ---- workspace layout (all regions 16B-aligned) ----
    float* bufD   = (float*)d_ws;          // mid fp32 [NN,128]      12.8 MB
    float* stats  = bufD + 3200000;        // 512 f (BN1 +0, BN2 +256)
    int* row_ptr  = (int*)(stats + 512);   // 25002
    int* cnt      = row_ptr + 25002;       // 25000
    int* col_src  = cnt + 25000;           // 425000
    int* bsum     = col_src + 425000;      // 132 (pad)
    float* fb1    = (float*)(bsum + 132);  // 768 fused bias L1
    float* fb2    = fb1 + 768;             // 768 fused bias L2
    u16* xb       = (u16*)(fb2 + 768);     // x bf16 [NN,128]         6.4 MB
    u16* XL       = xb + 3200000;          // [NN,384] bf16          19.2 MB
    u16* XR       = XL + 9600000;          // [NN,384] bf16 (MUST follow XL: split GEMM)
    u16* bufCat   = XR + 9600000;          // [NN,768] h2|x_in bf16  38.4 MB
    u16* bufDb    = bufCat + 19200000;     // h bf16 [NN,128]         6.4 MB
    u16* WfT1     = bufDb + 3200000;       // [768][128]
    u16* W1T      = WfT1 + 98304;          // [128][384]
    u16* WfT2     = W1T + 49152;           // [768][128]
    u16* W2T      = WfT2 + 98304;          // [128][768]

    // casts + transposes + fused biases + cnt init + stats zero, one kernel
    k_cast_all<<<(CAST_TOTAL + 255) / 256, 256, 0, stream>>>(
        x, Wl1, Wr1, W1, Wl2, Wr2, W2, bl1, br1, bl2, br2,
        xb, WfT1, W1T, WfT2, W2T, fb1, fb2, cnt, stats);

    // CSR (rebuilt every call — identical work each call)
    k_count<<<(NE + 255) / 256, 256, 0, stream>>>(edst, cnt);
    k_scan1<<<98, 256, 0, stream>>>(cnt, bsum);
    k_scan2<<<1, 128, 0, stream>>>(bsum, 98);
    k_scan3<<<98, 256, 0, stream>>>(cnt, bsum, row_ptr, col_src, cnt);
    k_fill_edges<<<(NE + 255) / 256, 256, 0, stream>>>(esrc, edst, cnt, col_src);

    dim3 blk(256);
    dim3 g768(6, (NN + 127) / 128);    // BN=128
    dim3 g128(2, (NN + 127) / 128);    // BN=64
    const int HB = 3125;               // NN/2/4 blocks per gat half

    // layer 1: [xl|xr] = x @ [Wl1|Wr1] -> XL,XR (split)
    k_gemm_bf<8, 1><<<g768, blk, 0, stream>>>(xb, WfT1, fb1, nullptr, XL, NN, 768, DD, DD);
    k_gat<<<HB, 256, 0, stream>>>((const u32*)XL, (const u32*)XR, att1, bc1,
                                  row_ptr, col_src, (u32*)bufCat + 192, 0);
    k_gat<<<HB, 256, 0, stream>>>((const u32*)XL, (const u32*)XR, att1, bc1,
                                  row_ptr, col_src, (u32*)bufCat + 192, NN / 2);

    // mid MLP + BN + relu  (A = x_in at bufCat cols 384.., lda=768)
    k_gemm_bf<4, 0><<<g128, blk, 0, stream>>>(bufCat + 384, W1T, b1, bufD, nullptr, NN, DD, HD, 768);
    k_bn_stats<<<128, 256, 0, stream>>>(bufD, stats);
    k_bn_apply<<<(NN * DD + 255) / 256, 256, 0, stream>>>(bufD, stats, g1, be1, bufDb, 0);

    // layer 2
    k_gemm_bf<8, 1><<<g768, blk, 0, stream>>>(bufDb, WfT2, fb2, nullptr, XL, NN, 768, DD, DD);
    k_gat<<<HB, 256, 0, stream>>>((const u32*)XL, (const u32*)XR, att2, bc2,
                                  row_ptr, col_src, (u32*)bufCat, 0);
    k_gat<<<HB, 256, 0, stream>>>((const u32*)XL, (const u32*)XR, att2, bc2,
                                  row_ptr, col_src, (u32*)bufCat, NN / 2);

    // final: concat([h2, x_in]) @ W2 + b2 as one K=768 GEMM, then BN+relu
    k_gemm_bf<4, 0><<<g128, blk, 0, stream>>>(bufCat, W2T, b2, out, nullptr, NN, DD, 768, 768);
    k_bn_stats<<<128, 256, 0, stream>>>(out, stats + 256);
    k_bn_apply<<<(NN * DD + 255) / 256, 256, 0, stream>>>(out, stats + 256, g2, be2, nullptr, 1);
}

// Round 8
// 496.951 us; speedup vs baseline: 1.1118x; 1.0284x over previous
//
#include <hip/hip_runtime.h>
#include <math.h>

#define NN 25000      // nodes
#define NE 400000     // edges
#define DD 128        // hidden dim
#define HD 384        // heads * dim
#define NEG 0.2f
#define EPS 1e-5f

typedef unsigned int u32;
typedef unsigned short u16;
typedef __attribute__((ext_vector_type(8))) short short8;   // 8 bf16 (4 VGPRs)
typedef __attribute__((ext_vector_type(4))) float floatx4;  // MFMA accumulator

// ---- bf16 helpers (RNE) ----
__device__ __forceinline__ u32 bf16_1(float x) {
    u32 u = __float_as_uint(x);
    return (u + 0x7fffu + ((u >> 16) & 1u)) >> 16;
}
__device__ __forceinline__ float blo(u32 u) { return __uint_as_float(u << 16); }
__device__ __forceinline__ float bhi(u32 u) { return __uint_as_float(u & 0xffff0000u); }

__device__ __forceinline__ void up8(uint4 u, float* f) {
    f[0] = blo(u.x); f[1] = bhi(u.x); f[2] = blo(u.y); f[3] = bhi(u.y);
    f[4] = blo(u.z); f[5] = bhi(u.z); f[6] = blo(u.w); f[7] = bhi(u.w);
}

// ---------------- CSR construction (grouped by dst) ----------------

__global__ void k_count(const int* __restrict__ dst, int* __restrict__ cnt) {
    int e = blockIdx.x * 256 + threadIdx.x;
    if (e < NE) atomicAdd(&cnt[dst[e]], 1);
}

__global__ void k_scan1(const int* __restrict__ cnt, int* __restrict__ bsum) {
    __shared__ int sh[256];
    int i = blockIdx.x * 256 + threadIdx.x;
    sh[threadIdx.x] = (i < NN) ? cnt[i] : 0;
    __syncthreads();
    for (int o = 128; o >= 1; o >>= 1) {
        if ((int)threadIdx.x < o) sh[threadIdx.x] += sh[threadIdx.x + o];
        __syncthreads();
    }
    if (threadIdx.x == 0) bsum[blockIdx.x] = sh[0];
}

__global__ void k_scan2(int* __restrict__ bsum, int nblk) {
    __shared__ int sh[128];
    int v = ((int)threadIdx.x < nblk) ? bsum[threadIdx.x] : 0;
    sh[threadIdx.x] = v;
    __syncthreads();
    for (int o = 1; o < 128; o <<= 1) {
        int t = (threadIdx.x >= (unsigned)o) ? sh[threadIdx.x - o] : 0;
        __syncthreads();
        sh[threadIdx.x] += t;
        __syncthreads();
    }
    if ((int)threadIdx.x < nblk) bsum[threadIdx.x] = sh[threadIdx.x];
}

// scan3 + self-loop fill fused
__global__ void k_scan3(const int* __restrict__ cnt, const int* __restrict__ bsum,
                        int* __restrict__ row_ptr, int* __restrict__ col_src,
                        int* __restrict__ cur) {
    __shared__ int sh[256];
    int i = blockIdx.x * 256 + threadIdx.x;
    int v = (i < NN) ? cnt[i] : 0;
    sh[threadIdx.x] = v;
    __syncthreads();
    for (int o = 1; o < 256; o <<= 1) {
        int t = (threadIdx.x >= (unsigned)o) ? sh[threadIdx.x - o] : 0;
        __syncthreads();
        sh[threadIdx.x] += t;
        __syncthreads();
    }
    int base = blockIdx.x ? bsum[blockIdx.x - 1] : 0;
    if (i < NN) {
        int incl = base + sh[threadIdx.x];
        row_ptr[i + 1] = incl;
        int p = incl - v;
        col_src[p] = i;            // self loop first
        cur[i] = p + 1;
    }
    if (i == 0) row_ptr[0] = 0;
}

__global__ void k_fill_edges(const int* __restrict__ src, const int* __restrict__ dst,
                             int* __restrict__ cur, int* __restrict__ col_src) {
    int e = blockIdx.x * 256 + threadIdx.x;
    if (e < NE) { int p = atomicAdd(&cur[dst[e]], 1); col_src[p] = src[e]; }
}

// ---------------- one cast/init kernel for everything ----------------
// regions: x 400000 (x8 vectorized) | Wl1 49152 | Wr1 49152 | W1 49152
//          | Wl2 49152 | Wr2 49152 | W2 98304 | fb1 768 | fb2 768 | cnt 25000 | stats 512
__global__ void k_cast_all(const float* __restrict__ x,
                           const float* __restrict__ Wl1, const float* __restrict__ Wr1,
                           const float* __restrict__ W1,
                           const float* __restrict__ Wl2, const float* __restrict__ Wr2,
                           const float* __restrict__ W2,
                           const float* __restrict__ bl1, const float* __restrict__ br1,
                           const float* __restrict__ bl2, const float* __restrict__ br2,
                           u16* __restrict__ xb, u16* __restrict__ WfT1,
                           u16* __restrict__ W1T, u16* __restrict__ WfT2,
                           u16* __restrict__ W2T,
                           float* __restrict__ fb1, float* __restrict__ fb2,
                           int* __restrict__ cnt, float* __restrict__ stats) {
    int i = blockIdx.x * 256 + threadIdx.x;
    if (i < 400000) {   // x cast, 8 elems/thread, coalesced 16B writes
        const float4* xp = (const float4*)(x + (size_t)i * 8);
        float4 a = xp[0], b = xp[1];
        uint4 w;
        w.x = bf16_1(a.x) | (bf16_1(a.y) << 16);
        w.y = bf16_1(a.z) | (bf16_1(a.w) << 16);
        w.z = bf16_1(b.x) | (bf16_1(b.y) << 16);
        w.w = bf16_1(b.z) | (bf16_1(b.w) << 16);
        *(uint4*)(xb + (size_t)i * 8) = w;
        return;
    }
    i -= 400000;
    if (i < 49152) { int k = i / 384, n = i - k * 384; WfT1[n * 128 + k] = (u16)bf16_1(Wl1[i]); return; }
    i -= 49152;
    if (i < 49152) { int k = i / 384, n = i - k * 384; WfT1[(384 + n) * 128 + k] = (u16)bf16_1(Wr1[i]); return; }
    i -= 49152;
    if (i < 49152) { int k = i / 128, n = i - k * 128; W1T[n * 384 + k] = (u16)bf16_1(W1[i]); return; }
    i -= 49152;
    if (i < 49152) { int k = i / 384, n = i - k * 384; WfT2[n * 128 + k] = (u16)bf16_1(Wl2[i]); return; }
    i -= 49152;
    if (i < 49152) { int k = i / 384, n = i - k * 384; WfT2[(384 + n) * 128 + k] = (u16)bf16_1(Wr2[i]); return; }
    i -= 49152;
    if (i < 98304) { int k = i / 128, n = i - k * 128; W2T[n * 768 + k] = (u16)bf16_1(W2[i]); return; }
    i -= 98304;
    if (i < 768) { fb1[i] = (i < 384) ? bl1[i] : br1[i - 384]; return; }
    i -= 768;
    if (i < 768) { fb2[i] = (i < 384) ? bl2[i] : br2[i - 384]; return; }
    i -= 768;
    if (i < 25000) { cnt[i] = 1; return; }   // self loop
    i -= 25000;
    if (i < 512) stats[i] = 0.f;
}
#define CAST_TOTAL (400000 + 5 * 49152 + 98304 + 1536 + 25000 + 512)

// ---------------- bf16 MFMA GEMM: C[M,N] = A[M,K] @ BT[N,K]^T (+bias) ----------------
// BM=128, BN=NF*16, BK=64, 256 threads. global_load_lds(16B) staging with
// XOR-swizzled source addressing. Epilogue stages the output tile in LDS
// ([row][col] layout) and streams it out as 16B-coalesced dwordx4 stores —
// scalar u16/f32 stores were the R7 write-RMW bottleneck (56us @ 3% MfmaUtil).
// Exactly one of Cf (fp32, NF=4) / Cb (bf16) is non-null.
// SPLIT: Cb is XL base; col>=384 -> XL+NN*384 (XR), row stride 384.
template<int NF, int SPLIT>
__global__ __launch_bounds__(256) void k_gemm_bf(
        const u16* __restrict__ A, const u16* __restrict__ BT,
        const float* __restrict__ bias,
        float* __restrict__ Cf, u16* __restrict__ Cb,
        int M, int N, int K, int lda) {
    __shared__ short smem[16384];   // 32 KB: staging (sA|sB) then output tile
    short* sA = smem;               // 128*64 shorts
    short* sB = smem + 8192;        // NF*16*64 shorts
    int tid = threadIdx.x;
    int wv = tid >> 6, lane = tid & 63;
    int quad = lane >> 4, m16 = lane & 15;
    int sw = m16 & 7;
    int mb = blockIdx.y * 128, nb = blockIdx.x * (NF * 16);

    floatx4 acc[2][NF];
#pragma unroll
    for (int mf = 0; mf < 2; ++mf)
#pragma unroll
        for (int nf = 0; nf < NF; ++nf)
#pragma unroll
            for (int r = 0; r < 4; ++r) acc[mf][nf][r] = 0.f;

    for (int k0 = 0; k0 < K; k0 += 64) {
#pragma unroll
        for (int j = 0; j < 4; ++j) {
            int L = (wv * 4 + j) * 64 + lane;
            int r = L >> 3, c8 = (L & 7) ^ (r & 7);
            int gr = mb + r; gr = gr < M ? gr : M - 1;
            __builtin_amdgcn_global_load_lds(
                (const __attribute__((address_space(1))) void*)(A + (size_t)gr * lda + k0 + c8 * 8),
                (__attribute__((address_space(3))) void*)(sA + (size_t)(wv * 4 + j) * 512),
                16, 0, 0);
        }
#pragma unroll
        for (int j = 0; j < NF / 2; ++j) {
            int L = (wv * (NF / 2) + j) * 64 + lane;
            int r = L >> 3, c8 = (L & 7) ^ (r & 7);
            __builtin_amdgcn_global_load_lds(
                (const __attribute__((address_space(1))) void*)(BT + (size_t)(nb + r) * K + k0 + c8 * 8),
                (__attribute__((address_space(3))) void*)(sB + (size_t)(wv * (NF / 2) + j) * 512),
                16, 0, 0);
        }
        __syncthreads();
#pragma unroll
        for (int ks = 0; ks < 2; ++ks) {
            int t = (ks * 4 + quad) ^ sw;
            const short* pa = sA + t * 8;
            const short* pb = sB + t * 8;
            short8 a0 = *(const short8*)(pa + (wv * 32 + m16) * 64);
            short8 a1 = *(const short8*)(pa + (wv * 32 + 16 + m16) * 64);
#pragma unroll
            for (int nf = 0; nf < NF; ++nf) {
                short8 b = *(const short8*)(pb + (nf * 16 + m16) * 64);
                acc[0][nf] = __builtin_amdgcn_mfma_f32_16x16x32_bf16(a0, b, acc[0][nf], 0, 0, 0);
                acc[1][nf] = __builtin_amdgcn_mfma_f32_16x16x32_bf16(a1, b, acc[1][nf], 0, 0, 0);
            }
        }
        __syncthreads();
    }

    // ---- epilogue: stage tile in LDS, stream out coalesced ----
    if (Cb) {
        // bf16 tile [128][NF*16] u16
#pragma unroll
        for (int mf = 0; mf < 2; ++mf)
#pragma unroll
            for (int nf = 0; nf < NF; ++nf)
#pragma unroll
                for (int r = 0; r < 4; ++r) {
                    int row = wv * 32 + mf * 16 + quad * 4 + r;
                    int col = nf * 16 + m16;
                    float v = acc[mf][nf][r] + (bias ? bias[nb + col] : 0.f);
                    smem[row * (NF * 16) + col] = (short)bf16_1(v);
                }
        __syncthreads();
        u16* cb = Cb;
        int ldcb = N, coff = 0;
        if (SPLIT) { ldcb = 384; if (nb >= 384) { cb = Cb + (size_t)NN * 384; coff = 384; } }
#pragma unroll
        for (int i = 0; i < NF; ++i) {
            int u = i * 256 + tid;
            int row = u / (NF * 2), c8 = u % (NF * 2);
            int grow = mb + row;
            if (grow < M) {
                uint4 t = *(const uint4*)(smem + (size_t)u * 8);
                *(uint4*)(cb + (size_t)grow * ldcb + (nb - coff) + c8 * 8) = t;
            }
        }
    } else {
        // fp32 tile [128][NF*16] f32 (NF=4 -> 32 KB)
        float* fs = (float*)smem;
#pragma unroll
        for (int mf = 0; mf < 2; ++mf)
#pragma unroll
            for (int nf = 0; nf < NF; ++nf)
#pragma unroll
                for (int r = 0; r < 4; ++r) {
                    int row = wv * 32 + mf * 16 + quad * 4 + r;
                    int col = nf * 16 + m16;
                    fs[row * (NF * 16) + col] = acc[mf][nf][r] + (bias ? bias[nb + col] : 0.f);
                }
        __syncthreads();
#pragma unroll
        for (int i = 0; i < NF * 2; ++i) {
            int u = i * 256 + tid;
            int row = u / (NF * 4), c4 = u % (NF * 4);
            int grow = mb + row;
            if (grow < M) {
                float4 t = *(const float4*)(fs + (size_t)u * 4);
                *(float4*)(Cf + (size_t)grow * N + nb + c4 * 4) = t;
            }
        }
    }
}

// ---------------- GATv2 aggregate ----------------
// One wave per dst node (node range starts at nbase); 4 groups of 16 lanes;
// group g handles edges e0+g, e0+g+4, ... with guarded depth-1 prefetch.
// shfl_xor butterfly (LDS pipe) for the score reduce. Branchless online
// softmax. Flash-merge of 4 group states at end (-1e30 empty sentinel).
__global__ __launch_bounds__(256) void k_gat(const u32* __restrict__ XL,
                                             const u32* __restrict__ XR,
                                             const float* __restrict__ att,
                                             const float* __restrict__ bias,
                                             const int* __restrict__ row_ptr,
                                             const int* __restrict__ col_src,
                                             u32* __restrict__ outb, int nbase) {
    int node = nbase + blockIdx.x * 4 + (threadIdx.x >> 6);
    int lane = threadIdx.x & 63;
    int g = lane >> 4, gl = lane & 15;

    const u32* xrp = XR + (size_t)node * 192 + 4 * gl;
    float xr_f[3][8], att_f[3][8], acc[3][8], m[3], l[3];
#pragma unroll
    for (int h = 0; h < 3; ++h) {
        up8(*(const uint4*)(xrp + h * 64), xr_f[h]);
        *(float4*)&att_f[h][0] = *(const float4*)&att[h * 128 + 8 * gl];
        *(float4*)&att_f[h][4] = *(const float4*)&att[h * 128 + 8 * gl + 4];
#pragma unroll
        for (int k = 0; k < 8; ++k) acc[h][k] = 0.f;
        m[h] = -1e30f; l[h] = 0.f;
    }

    int e0 = row_ptr[node];
    int cntE = row_ptr[node + 1] - e0;

    uint4 u0 = {}, u1 = {}, u2 = {};
    if (g < cntE) {
        int s = col_src[e0 + g];
        const u32* xp = XL + (size_t)s * 192 + 4 * gl;
        u0 = *(const uint4*)xp; u1 = *(const uint4*)(xp + 64); u2 = *(const uint4*)(xp + 128);
    }
    for (int t = g; t < cntE; t += 4) {
        float xv[3][8];
        up8(u0, xv[0]); up8(u1, xv[1]); up8(u2, xv[2]);
        int tn = t + 4;
        if (tn < cntE) {   // guarded depth-1 prefetch
            int s = col_src[e0 + tn];
            const u32* xp = XL + (size_t)s * 192 + 4 * gl;
            u0 = *(const uint4*)xp; u1 = *(const uint4*)(xp + 64); u2 = *(const uint4*)(xp + 128);
        }
        float p[3];
#pragma unroll
        for (int h = 0; h < 3; ++h) {
            float ph = 0.f;
#pragma unroll
            for (int k = 0; k < 8; ++k) {
                float v = xv[h][k] + xr_f[h][k];
                ph = fmaf(fmaxf(v, NEG * v), att_f[h][k], ph);
            }
            p[h] = ph;
        }
#pragma unroll
        for (int o = 1; o <= 8; o <<= 1) {
            p[0] += __shfl_xor(p[0], o);
            p[1] += __shfl_xor(p[1], o);
            p[2] += __shfl_xor(p[2], o);
        }
#pragma unroll
        for (int h = 0; h < 3; ++h) {
            float mn = fmaxf(m[h], p[h]);
            float c = __expf(m[h] - mn), w = __expf(p[h] - mn);
            l[h] = fmaf(l[h], c, w);
            m[h] = mn;
#pragma unroll
            for (int k = 0; k < 8; ++k)
                acc[h][k] = fmaf(acc[h][k], c, w * xv[h][k]);
        }
    }

    // merge the 4 group states (empty group: m=-1e30, l=0, acc=0 -> adds 0)
#pragma unroll
    for (int o = 16; o <= 32; o <<= 1) {
#pragma unroll
        for (int h = 0; h < 3; ++h) {
            float mo = __shfl_xor(m[h], o);
            float lo = __shfl_xor(l[h], o);
            float mn = fmaxf(m[h], mo);
            float cs = __expf(m[h] - mn);
            float co = __expf(mo - mn);
            l[h] = l[h] * cs + lo * co;
            m[h] = mn;
#pragma unroll
            for (int k = 0; k < 8; ++k)
                acc[h][k] = acc[h][k] * cs + __shfl_xor(acc[h][k], o) * co;
        }
    }

    if (g < 3) {   // group g writes head g (merged state identical in all lanes)
        int h = g;
        float r = 1.f / l[h];
        float bv[8];
        *(float4*)&bv[0] = *(const float4*)&bias[h * 128 + 8 * gl];
        *(float4*)&bv[4] = *(const float4*)&bias[h * 128 + 8 * gl + 4];
        uint4 w;
        w.x = bf16_1(fmaf(acc[h][0], r, bv[0])) | (bf16_1(fmaf(acc[h][1], r, bv[1])) << 16);
        w.y = bf16_1(fmaf(acc[h][2], r, bv[2])) | (bf16_1(fmaf(acc[h][3], r, bv[3])) << 16);
        w.z = bf16_1(fmaf(acc[h][4], r, bv[4])) | (bf16_1(fmaf(acc[h][5], r, bv[5])) << 16);
        w.w = bf16_1(fmaf(acc[h][6], r, bv[6])) | (bf16_1(fmaf(acc[h][7], r, bv[7])) << 16);
        *(uint4*)(outb + (size_t)node * 384 + h * 64 + 4 * gl) = w;
    }
}

// ---------------- BatchNorm (axis=0 over N rows, 128 cols) ----------------

__global__ void k_bn_stats(const float* __restrict__ y, float* __restrict__ stats) {
    int col = threadIdx.x & 127;
    int half = threadIdx.x >> 7;
    float s = 0.f, q = 0.f;
    for (int r = blockIdx.x * 2 + half; r < NN; r += gridDim.x * 2) {
        float v = y[(size_t)r * DD + col];
        s += v; q += v * v;
    }
    __shared__ float sh[256], shq[256];
    sh[threadIdx.x] = s; shq[threadIdx.x] = q;
    __syncthreads();
    if (half == 0) {
        atomicAdd(&stats[col], sh[col] + sh[col + 128]);
        atomicAdd(&stats[128 + col], shq[col] + shq[col + 128]);
    }
}

// 8 elems/thread, vectorized loads+stores. finalize folded in.
__global__ void k_bn_apply(float* __restrict__ y, const float* __restrict__ stats,
                           const float* __restrict__ g, const float* __restrict__ be,
                           u16* __restrict__ yb, int wf) {
    int i = blockIdx.x * 256 + threadIdx.x;
    if (i >= NN * DD / 8) return;
    int idx = i * 8;
    int c0 = idx & 127;
    float v[8];
    *(float4*)&v[0] = *(const float4*)(y + idx);
    *(float4*)&v[4] = *(const float4*)(y + idx + 4);
    const float minv = 1.f / (float)NN;
#pragma unroll
    for (int k = 0; k < 8; ++k) {
        int c = c0 + k;
        float mu = stats[c] * minv;
        float var = stats[128 + c] * minv - mu * mu;
        float sc = g[c] * rsqrtf(var + EPS);
        float sh = be[c] - mu * sc;
        v[k] = fmaxf(fmaf(v[k], sc, sh), 0.f);
    }
    if (wf) {
        *(float4*)(y + idx) = *(const float4*)&v[0];
        *(float4*)(y + idx + 4) = *(const float4*)&v[4];
    }
    if (yb) {
        uint4 w;
        w.x = bf16_1(v[0]) | (bf16_1(v[1]) << 16);
        w.y = bf16_1(v[2]) | (bf16_1(v[3]) << 16);
        w.z = bf16_1(v[4]) | (bf16_1(v[5]) << 16);
        w.w = bf16_1(v[6]) | (bf16_1(v[7]) << 16);
        *(uint4*)(yb + idx) = w;
    }
}

// ---------------- launch ----------------

extern "C" void kernel_launch(void* const* d_in, const int* in_sizes, int n_in,
                              void* d_out, int out_size, void* d_ws, size_t ws_size,
                              hipStream_t stream) {
    const float* x    = (const float*)d_in[0];
    const int*   ei   = (const int*)d_in[1];
    const float* Wl1  = (const float*)d_in[2];
    const float* bl1  = (const float*)d_in[3];
    const float* Wr1  = (const float*)d_in[4];
    const float* br1  = (const float*)d_in[5];
    const float* att1 = (const float*)d_in[6];
    const float* bc1  = (const float*)d_in[7];
    const float* g1   = (const float*)d_in[8];
    const float* be1  = (const float*)d_in[9];
    const float* Wl2  = (const float*)d_in[10];
    const float* bl2  = (const float*)d_in[11];
    const float* Wr2  = (const float*)d_in[12];
    const float* br2  = (const float*)d_in[13];
    const float* att2 = (const float*)d_in[14];
    const float* bc2  = (const float*)d_in[15];
    const float* g2   = (const float*)d_in[16];
    const float* be2  = (const float*)d_in[17];
    const float* W1   = (const float*)d_in[18];
    const float* b1   = (const float*)d_in[19];
    const float* W2   = (const float*)d_in[20];
    const float* b2   = (const float*)d_in[21];
    const int* esrc = ei;
    const int* edst = ei + NE;
    float* out = (float*)d_out;

    // ---- workspace layout (all regions 16B-aligned) ----
    float* bufD   = (float*)d_ws;          // mid fp32 [NN,128]      12.8 MB
    float* stats  = bufD + 3200000;        // 512 f (BN1 +0, BN2 +256)
    int* row_ptr  = (int*)(stats + 512);   // 25002
    int* cnt      = row_ptr + 25002;       // 25000
    int* col_src  = cnt + 25000;           // 425000
    int* bsum     = col_src + 425000;      // 132 (pad)
    float* fb1    = (float*)(bsum + 132);  // 768 fused bias L1
    float* fb2    = fb1 + 768;             // 768 fused bias L2
    u16* xb       = (u16*)(fb2 + 768);     // x bf16 [NN,128]         6.4 MB
    u16* XL       = xb + 3200000;          // [NN,384] bf16          19.2 MB
    u16* XR       = XL + 9600000;          // [NN,384] bf16 (MUST follow XL: split GEMM)
    u16* bufCat   = XR + 9600000;          // [NN,768] h2|x_in bf16  38.4 MB
    u16* bufDb    = bufCat + 19200000;     // h bf16 [NN,128]         6.4 MB
    u16* WfT1     = bufDb + 3200000;       // [768][128]
    u16* W1T      = WfT1 + 98304;          // [128][384]
    u16* WfT2     = W1T + 49152;           // [768][128]
    u16* W2T      = WfT2 + 98304;          // [128][768]

    // casts + transposes + fused biases + cnt init + stats zero, one kernel
    k_cast_all<<<(CAST_TOTAL + 255) / 256, 256, 0, stream>>>(
        x, Wl1, Wr1, W1, Wl2, Wr2, W2, bl1, br1, bl2, br2,
        xb, WfT1, W1T, WfT2, W2T, fb1, fb2, cnt, stats);

    // CSR (rebuilt every call — identical work each call)
    k_count<<<(NE + 255) / 256, 256, 0, stream>>>(edst, cnt);
    k_scan1<<<98, 256, 0, stream>>>(cnt, bsum);
    k_scan2<<<1, 128, 0, stream>>>(bsum, 98);
    k_scan3<<<98, 256, 0, stream>>>(cnt, bsum, row_ptr, col_src, cnt);
    k_fill_edges<<<(NE + 255) / 256, 256, 0, stream>>>(esrc, edst, cnt, col_src);

    dim3 blk(256);
    dim3 g768(6, (NN + 127) / 128);    // BN=128
    dim3 g128(2, (NN + 127) / 128);    // BN=64
    const int HB = 3125;               // NN/2/4 blocks per gat half

    // layer 1: [xl|xr] = x @ [Wl1|Wr1] -> XL,XR (split)
    k_gemm_bf<8, 1><<<g768, blk, 0, stream>>>(xb, WfT1, fb1, nullptr, XL, NN, 768, DD, DD);
    k_gat<<<HB, 256, 0, stream>>>((const u32*)XL, (const u32*)XR, att1, bc1,
                                  row_ptr, col_src, (u32*)bufCat + 192, 0);
    k_gat<<<HB, 256, 0, stream>>>((const u32*)XL, (const u32*)XR, att1, bc1,
                                  row_ptr, col_src, (u32*)bufCat + 192, NN / 2);

    // mid MLP + BN + relu  (A = x_in at bufCat cols 384.., lda=768)
    k_gemm_bf<4, 0><<<g128, blk, 0, stream>>>(bufCat + 384, W1T, b1, bufD, nullptr, NN, DD, HD, 768);
    k_bn_stats<<<128, 256, 0, stream>>>(bufD, stats);
    k_bn_apply<<<(NN * DD / 8 + 255) / 256, 256, 0, stream>>>(bufD, stats, g1, be1, bufDb, 0);

    // layer 2
    k_gemm_bf<8, 1><<<g768, blk, 0, stream>>>(bufDb, WfT2, fb2, nullptr, XL, NN, 768, DD, DD);
    k_gat<<<HB, 256, 0, stream>>>((const u32*)XL, (const u32*)XR, att2, bc2,
                                  row_ptr, col_src, (u32*)bufCat, 0);
    k_gat<<<HB, 256, 0, stream>>>((const u32*)XL, (const u32*)XR, att2, bc2,
                                  row_ptr, col_src, (u32*)bufCat, NN / 2);

    // final: concat([h2, x_in]) @ W2 + b2 as one K=768 GEMM, then BN+relu
    k_gemm_bf<4, 0><<<g128, blk, 0, stream>>>(bufCat, W2T, b2, out, nullptr, NN, DD, 768, 768);
    k_bn_stats<<<128, 256, 0, stream>>>(out, stats + 256);
    k_bn_apply<<<(NN * DD / 8 + 255) / 256, 256, 0, stream>>>(out, stats + 256, g2, be2, nullptr, 1);
}

// Round 9
// 461.495 us; speedup vs baseline: 1.1972x; 1.0768x over previous
//
#include <hip/hip_runtime.h>
#include <math.h>

#define NN 25000      // nodes
#define NE 400000     // edges
#define DD 128        // hidden dim
#define HD 384        // heads * dim
#define NEG 0.2f
#define EPS 1e-5f

typedef unsigned int u32;
typedef unsigned short u16;
typedef __attribute__((ext_vector_type(8))) short short8;   // 8 bf16 (4 VGPRs)
typedef __attribute__((ext_vector_type(4))) float floatx4;  // MFMA accumulator

// ---- bf16 helpers (RNE) ----
__device__ __forceinline__ u32 bf16_1(float x) {
    u32 u = __float_as_uint(x);
    return (u + 0x7fffu + ((u >> 16) & 1u)) >> 16;
}
__device__ __forceinline__ float blo(u32 u) { return __uint_as_float(u << 16); }
__device__ __forceinline__ float bhi(u32 u) { return __uint_as_float(u & 0xffff0000u); }

__device__ __forceinline__ void up8(uint4 u, float* f) {
    f[0] = blo(u.x); f[1] = bhi(u.x); f[2] = blo(u.y); f[3] = bhi(u.y);
    f[4] = blo(u.z); f[5] = bhi(u.z); f[6] = blo(u.w); f[7] = bhi(u.w);
}

// ---------------- CSR construction (grouped by dst) ----------------

__global__ void k_count(const int* __restrict__ dst, int* __restrict__ cnt) {
    int e = blockIdx.x * 256 + threadIdx.x;
    if (e < NE) atomicAdd(&cnt[dst[e]], 1);
}

__global__ void k_scan1(const int* __restrict__ cnt, int* __restrict__ bsum) {
    __shared__ int sh[256];
    int i = blockIdx.x * 256 + threadIdx.x;
    sh[threadIdx.x] = (i < NN) ? cnt[i] : 0;
    __syncthreads();
    for (int o = 128; o >= 1; o >>= 1) {
        if ((int)threadIdx.x < o) sh[threadIdx.x] += sh[threadIdx.x + o];
        __syncthreads();
    }
    if (threadIdx.x == 0) bsum[blockIdx.x] = sh[0];
}

__global__ void k_scan2(int* __restrict__ bsum, int nblk) {
    __shared__ int sh[128];
    int v = ((int)threadIdx.x < nblk) ? bsum[threadIdx.x] : 0;
    sh[threadIdx.x] = v;
    __syncthreads();
    for (int o = 1; o < 128; o <<= 1) {
        int t = (threadIdx.x >= (unsigned)o) ? sh[threadIdx.x - o] : 0;
        __syncthreads();
        sh[threadIdx.x] += t;
        __syncthreads();
    }
    if ((int)threadIdx.x < nblk) bsum[threadIdx.x] = sh[threadIdx.x];
}

// scan3 + self-loop fill fused
__global__ void k_scan3(const int* __restrict__ cnt, const int* __restrict__ bsum,
                        int* __restrict__ row_ptr, int* __restrict__ col_src,
                        int* __restrict__ cur) {
    __shared__ int sh[256];
    int i = blockIdx.x * 256 + threadIdx.x;
    int v = (i < NN) ? cnt[i] : 0;
    sh[threadIdx.x] = v;
    __syncthreads();
    for (int o = 1; o < 256; o <<= 1) {
        int t = (threadIdx.x >= (unsigned)o) ? sh[threadIdx.x - o] : 0;
        __syncthreads();
        sh[threadIdx.x] += t;
        __syncthreads();
    }
    int base = blockIdx.x ? bsum[blockIdx.x - 1] : 0;
    if (i < NN) {
        int incl = base + sh[threadIdx.x];
        row_ptr[i + 1] = incl;
        int p = incl - v;
        col_src[p] = i;            // self loop first
        cur[i] = p + 1;
    }
    if (i == 0) row_ptr[0] = 0;
}

__global__ void k_fill_edges(const int* __restrict__ src, const int* __restrict__ dst,
                             int* __restrict__ cur, int* __restrict__ col_src) {
    int e = blockIdx.x * 256 + threadIdx.x;
    if (e < NE) { int p = atomicAdd(&cur[dst[e]], 1); col_src[p] = src[e]; }
}

// ---------------- one cast/init kernel for everything ----------------
__global__ void k_cast_all(const float* __restrict__ x,
                           const float* __restrict__ Wl1, const float* __restrict__ Wr1,
                           const float* __restrict__ W1,
                           const float* __restrict__ Wl2, const float* __restrict__ Wr2,
                           const float* __restrict__ W2,
                           const float* __restrict__ bl1, const float* __restrict__ br1,
                           const float* __restrict__ bl2, const float* __restrict__ br2,
                           u16* __restrict__ xb, u16* __restrict__ WfT1,
                           u16* __restrict__ W1T, u16* __restrict__ WfT2,
                           u16* __restrict__ W2T,
                           float* __restrict__ fb1, float* __restrict__ fb2,
                           int* __restrict__ cnt, float* __restrict__ stats) {
    int i = blockIdx.x * 256 + threadIdx.x;
    if (i < 400000) {   // x cast, 8 elems/thread, coalesced 16B writes
        const float4* xp = (const float4*)(x + (size_t)i * 8);
        float4 a = xp[0], b = xp[1];
        uint4 w;
        w.x = bf16_1(a.x) | (bf16_1(a.y) << 16);
        w.y = bf16_1(a.z) | (bf16_1(a.w) << 16);
        w.z = bf16_1(b.x) | (bf16_1(b.y) << 16);
        w.w = bf16_1(b.z) | (bf16_1(b.w) << 16);
        *(uint4*)(xb + (size_t)i * 8) = w;
        return;
    }
    i -= 400000;
    if (i < 49152) { int k = i / 384, n = i - k * 384; WfT1[n * 128 + k] = (u16)bf16_1(Wl1[i]); return; }
    i -= 49152;
    if (i < 49152) { int k = i / 384, n = i - k * 384; WfT1[(384 + n) * 128 + k] = (u16)bf16_1(Wr1[i]); return; }
    i -= 49152;
    if (i < 49152) { int k = i / 128, n = i - k * 128; W1T[n * 384 + k] = (u16)bf16_1(W1[i]); return; }
    i -= 49152;
    if (i < 49152) { int k = i / 384, n = i - k * 384; WfT2[n * 128 + k] = (u16)bf16_1(Wl2[i]); return; }
    i -= 49152;
    if (i < 49152) { int k = i / 384, n = i - k * 384; WfT2[(384 + n) * 128 + k] = (u16)bf16_1(Wr2[i]); return; }
    i -= 49152;
    if (i < 98304) { int k = i / 128, n = i - k * 128; W2T[n * 768 + k] = (u16)bf16_1(W2[i]); return; }
    i -= 98304;
    if (i < 768) { fb1[i] = (i < 384) ? bl1[i] : br1[i - 384]; return; }
    i -= 768;
    if (i < 768) { fb2[i] = (i < 384) ? bl2[i] : br2[i - 384]; return; }
    i -= 768;
    if (i < 25000) { cnt[i] = 1; return; }   // self loop
    i -= 25000;
    if (i < 512) stats[i] = 0.f;
}
#define CAST_TOTAL (400000 + 5 * 49152 + 98304 + 1536 + 25000 + 512)

// ---------------- bf16 MFMA GEMM: C[M,N] = A[M,K] @ BT[N,K]^T (+bias) ----------------
// BM=128, BN=NF*16, BK=64. global_load_lds(16B) staging, XOR-swizzled source.
// LDS-staged coalesced epilogue. SPLIT (requires NF=8, N=768): head-major
// output — col tile [nb,nb+128) is one head: xl heads at Cb + h*NN*128,
// xr heads at Cb + NN*384 + h*NN*128, row stride 128.
template<int NF, int SPLIT>
__global__ __launch_bounds__(256) void k_gemm_bf(
        const u16* __restrict__ A, const u16* __restrict__ BT,
        const float* __restrict__ bias,
        float* __restrict__ Cf, u16* __restrict__ Cb,
        int M, int N, int K, int lda) {
    __shared__ short smem[16384];   // 32 KB: staging (sA|sB) then output tile
    short* sA = smem;               // 128*64 shorts
    short* sB = smem + 8192;        // NF*16*64 shorts
    int tid = threadIdx.x;
    int wv = tid >> 6, lane = tid & 63;
    int quad = lane >> 4, m16 = lane & 15;
    int sw = m16 & 7;
    int mb = blockIdx.y * 128, nb = blockIdx.x * (NF * 16);

    floatx4 acc[2][NF];
#pragma unroll
    for (int mf = 0; mf < 2; ++mf)
#pragma unroll
        for (int nf = 0; nf < NF; ++nf)
#pragma unroll
            for (int r = 0; r < 4; ++r) acc[mf][nf][r] = 0.f;

    for (int k0 = 0; k0 < K; k0 += 64) {
#pragma unroll
        for (int j = 0; j < 4; ++j) {
            int L = (wv * 4 + j) * 64 + lane;
            int r = L >> 3, c8 = (L & 7) ^ (r & 7);
            int gr = mb + r; gr = gr < M ? gr : M - 1;
            __builtin_amdgcn_global_load_lds(
                (const __attribute__((address_space(1))) void*)(A + (size_t)gr * lda + k0 + c8 * 8),
                (__attribute__((address_space(3))) void*)(sA + (size_t)(wv * 4 + j) * 512),
                16, 0, 0);
        }
#pragma unroll
        for (int j = 0; j < NF / 2; ++j) {
            int L = (wv * (NF / 2) + j) * 64 + lane;
            int r = L >> 3, c8 = (L & 7) ^ (r & 7);
            __builtin_amdgcn_global_load_lds(
                (const __attribute__((address_space(1))) void*)(BT + (size_t)(nb + r) * K + k0 + c8 * 8),
                (__attribute__((address_space(3))) void*)(sB + (size_t)(wv * (NF / 2) + j) * 512),
                16, 0, 0);
        }
        __syncthreads();
#pragma unroll
        for (int ks = 0; ks < 2; ++ks) {
            int t = (ks * 4 + quad) ^ sw;
            const short* pa = sA + t * 8;
            const short* pb = sB + t * 8;
            short8 a0 = *(const short8*)(pa + (wv * 32 + m16) * 64);
            short8 a1 = *(const short8*)(pa + (wv * 32 + 16 + m16) * 64);
#pragma unroll
            for (int nf = 0; nf < NF; ++nf) {
                short8 b = *(const short8*)(pb + (nf * 16 + m16) * 64);
                acc[0][nf] = __builtin_amdgcn_mfma_f32_16x16x32_bf16(a0, b, acc[0][nf], 0, 0, 0);
                acc[1][nf] = __builtin_amdgcn_mfma_f32_16x16x32_bf16(a1, b, acc[1][nf], 0, 0, 0);
            }
        }
        __syncthreads();
    }

    // ---- epilogue: stage tile in LDS, stream out coalesced ----
    if (Cb) {
        // bf16 tile [128][NF*16] u16
#pragma unroll
        for (int mf = 0; mf < 2; ++mf)
#pragma unroll
            for (int nf = 0; nf < NF; ++nf)
#pragma unroll
                for (int r = 0; r < 4; ++r) {
                    int row = wv * 32 + mf * 16 + quad * 4 + r;
                    int col = nf * 16 + m16;
                    float v = acc[mf][nf][r] + (bias ? bias[nb + col] : 0.f);
                    smem[row * (NF * 16) + col] = (short)bf16_1(v);
                }
        __syncthreads();
        u16* cb;
        size_t ldcb;
        int cbase;
        if (SPLIT) {   // head-major: tile is exactly one head's 128 cols
            int h, xr = nb >= 384;
            h = (xr ? (nb - 384) : nb) >> 7;
            cb = Cb + ((size_t)(xr * 3 + h) * NN) * 128;
            ldcb = 128; cbase = 0;
        } else {
            cb = Cb; ldcb = N; cbase = nb;
        }
#pragma unroll
        for (int i = 0; i < NF; ++i) {
            int u = i * 256 + tid;
            int row = u / (NF * 2), c8 = u % (NF * 2);
            int grow = mb + row;
            if (grow < M) {
                uint4 t = *(const uint4*)(smem + (size_t)u * 8);
                *(uint4*)(cb + (size_t)grow * ldcb + cbase + c8 * 8) = t;
            }
        }
    } else {
        // fp32 tile [128][NF*16] f32 (NF=4 -> 32 KB)
        float* fs = (float*)smem;
#pragma unroll
        for (int mf = 0; mf < 2; ++mf)
#pragma unroll
            for (int nf = 0; nf < NF; ++nf)
#pragma unroll
                for (int r = 0; r < 4; ++r) {
                    int row = wv * 32 + mf * 16 + quad * 4 + r;
                    int col = nf * 16 + m16;
                    fs[row * (NF * 16) + col] = acc[mf][nf][r] + (bias ? bias[nb + col] : 0.f);
                }
        __syncthreads();
#pragma unroll
        for (int i = 0; i < NF * 2; ++i) {
            int u = i * 256 + tid;
            int row = u / (NF * 4), c4 = u % (NF * 4);
            int grow = mb + row;
            if (grow < M) {
                float4 t = *(const float4*)(fs + (size_t)u * 4);
                *(float4*)(Cf + (size_t)grow * N + nb + c4 * 4) = t;
            }
        }
    }
}

// ---------------- GATv2 aggregate, ONE HEAD per dispatch ----------------
// XLh/XRh: head-major [NN][64-dword] bf16 rows (256B per node-head). One wave
// per dst node; 4 groups of 16 lanes; group g handles edges e0+g, e0+g+4,...
// with depth-2 clamped prefetch (2 edge rows in flight). shfl_xor butterfly
// score reduce (LDS pipe). Branchless online softmax. Flash-merge of the 4
// group states at end (-1e30 empty sentinel). outb pre-offset for head slot;
// row stride 384 dwords.
__global__ __launch_bounds__(256) void k_gat_h(const u32* __restrict__ XLh,
                                               const u32* __restrict__ XRh,
                                               const float* __restrict__ att_h,
                                               const float* __restrict__ bias_h,
                                               const int* __restrict__ row_ptr,
                                               const int* __restrict__ col_src,
                                               u32* __restrict__ outb) {
    int node = blockIdx.x * 4 + (threadIdx.x >> 6);
    int lane = threadIdx.x & 63;
    int g = lane >> 4, gl = lane & 15;

    float xr_f[8], att_f[8], acc[8];
    up8(*(const uint4*)(XRh + (size_t)node * 64 + 4 * gl), xr_f);
    *(float4*)&att_f[0] = *(const float4*)&att_h[8 * gl];
    *(float4*)&att_f[4] = *(const float4*)&att_h[8 * gl + 4];
#pragma unroll
    for (int k = 0; k < 8; ++k) acc[k] = 0.f;
    float m = -1e30f, l = 0.f;

    int e0 = row_ptr[node];
    int cntE = row_ptr[node + 1] - e0;
    int elast = e0 + cntE - 1;

    // depth-2 clamped prefetch
    int ea = e0 + g;     ea = ea < elast ? ea : elast;
    int eb = e0 + g + 4; eb = eb < elast ? eb : elast;
    uint4 ua = *(const uint4*)(XLh + (size_t)col_src[ea] * 64 + 4 * gl);
    uint4 ub = *(const uint4*)(XLh + (size_t)col_src[eb] * 64 + 4 * gl);

    for (int t = g; t < cntE; t += 4) {
        int en = e0 + t + 8; en = en < elast ? en : elast;
        uint4 un = *(const uint4*)(XLh + (size_t)col_src[en] * 64 + 4 * gl);

        float xv[8];
        up8(ua, xv);
        float p = 0.f;
#pragma unroll
        for (int k = 0; k < 8; ++k) {
            float v = xv[k] + xr_f[k];
            p = fmaf(fmaxf(v, NEG * v), att_f[k], p);
        }
#pragma unroll
        for (int o = 1; o <= 8; o <<= 1) p += __shfl_xor(p, o);

        float mn = fmaxf(m, p);
        float c = __expf(m - mn), w = __expf(p - mn);
        l = fmaf(l, c, w);
        m = mn;
#pragma unroll
        for (int k = 0; k < 8; ++k) acc[k] = fmaf(acc[k], c, w * xv[k]);

        ua = ub; ub = un;
    }

    // merge the 4 group states (empty group: m=-1e30, l=0, acc=0 -> adds 0)
#pragma unroll
    for (int o = 16; o <= 32; o <<= 1) {
        float mo = __shfl_xor(m, o);
        float lo = __shfl_xor(l, o);
        float mn = fmaxf(m, mo);
        float cs = __expf(m - mn);
        float co = __expf(mo - mn);
        l = l * cs + lo * co;
        m = mn;
#pragma unroll
        for (int k = 0; k < 8; ++k)
            acc[k] = acc[k] * cs + __shfl_xor(acc[k], o) * co;
    }

    if (g == 0) {   // merged state identical in all lanes of group 0
        float r = 1.f / l;
        float bv[8];
        *(float4*)&bv[0] = *(const float4*)&bias_h[8 * gl];
        *(float4*)&bv[4] = *(const float4*)&bias_h[8 * gl + 4];
        uint4 w;
        w.x = bf16_1(fmaf(acc[0], r, bv[0])) | (bf16_1(fmaf(acc[1], r, bv[1])) << 16);
        w.y = bf16_1(fmaf(acc[2], r, bv[2])) | (bf16_1(fmaf(acc[3], r, bv[3])) << 16);
        w.z = bf16_1(fmaf(acc[4], r, bv[4])) | (bf16_1(fmaf(acc[5], r, bv[5])) << 16);
        w.w = bf16_1(fmaf(acc[6], r, bv[6])) | (bf16_1(fmaf(acc[7], r, bv[7])) << 16);
        *(uint4*)(outb + (size_t)node * 384 + 4 * gl) = w;
    }
}

// ---------------- BatchNorm (axis=0 over N rows, 128 cols) ----------------

__global__ void k_bn_stats(const float* __restrict__ y, float* __restrict__ stats) {
    int col = threadIdx.x & 127;
    int half = threadIdx.x >> 7;
    float s = 0.f, q = 0.f;
    for (int r = blockIdx.x * 2 + half; r < NN; r += gridDim.x * 2) {
        float v = y[(size_t)r * DD + col];
        s += v; q += v * v;
    }
    __shared__ float sh[256], shq[256];
    sh[threadIdx.x] = s; shq[threadIdx.x] = q;
    __syncthreads();
    if (half == 0) {
        atomicAdd(&stats[col], sh[col] + sh[col + 128]);
        atomicAdd(&stats[128 + col], shq[col] + shq[col + 128]);
    }
}

// 8 elems/thread, vectorized loads+stores. finalize folded in.
__global__ void k_bn_apply(float* __restrict__ y, const float* __restrict__ stats,
                           const float* __restrict__ g, const float* __restrict__ be,
                           u16* __restrict__ yb, int wf) {
    int i = blockIdx.x * 256 + threadIdx.x;
    if (i >= NN * DD / 8) return;
    int idx = i * 8;
    int c0 = idx & 127;
    float v[8];
    *(float4*)&v[0] = *(const float4*)(y + idx);
    *(float4*)&v[4] = *(const float4*)(y + idx + 4);
    const float minv = 1.f / (float)NN;
#pragma unroll
    for (int k = 0; k < 8; ++k) {
        int c = c0 + k;
        float mu = stats[c] * minv;
        float var = stats[128 + c] * minv - mu * mu;
        float sc = g[c] * rsqrtf(var + EPS);
        float sh = be[c] - mu * sc;
        v[k] = fmaxf(fmaf(v[k], sc, sh), 0.f);
    }
    if (wf) {
        *(float4*)(y + idx) = *(const float4*)&v[0];
        *(float4*)(y + idx + 4) = *(const float4*)&v[4];
    }
    if (yb) {
        uint4 w;
        w.x = bf16_1(v[0]) | (bf16_1(v[1]) << 16);
        w.y = bf16_1(v[2]) | (bf16_1(v[3]) << 16);
        w.z = bf16_1(v[4]) | (bf16_1(v[5]) << 16);
        w.w = bf16_1(v[6]) | (bf16_1(v[7]) << 16);
        *(uint4*)(yb + idx) = w;
    }
}

// ---------------- launch ----------------

extern "C" void kernel_launch(void* const* d_in, const int* in_sizes, int n_in,
                              void* d_out, int out_size, void* d_ws, size_t ws_size,
                              hipStream_t stream) {
    const float* x    = (const float*)d_in[0];
    const int*   ei   = (const int*)d_in[1];
    const float* Wl1  = (const float*)d_in[2];
    const float* bl1  = (const float*)d_in[3];
    const float* Wr1  = (const float*)d_in[4];
    const float* br1  = (const float*)d_in[5];
    const float* att1 = (const float*)d_in[6];
    const float* bc1  = (const float*)d_in[7];
    const float* g1   = (const float*)d_in[8];
    const float* be1  = (const float*)d_in[9];
    const float* Wl2  = (const float*)d_in[10];
    const float* bl2  = (const float*)d_in[11];
    const float* Wr2  = (const float*)d_in[12];
    const float* br2  = (const float*)d_in[13];
    const float* att2 = (const float*)d_in[14];
    const float* bc2  = (const float*)d_in[15];
    const float* g2   = (const float*)d_in[16];
    const float* be2  = (const float*)d_in[17];
    const float* W1   = (const float*)d_in[18];
    const float* b1   = (const float*)d_in[19];
    const float* W2   = (const float*)d_in[20];
    const float* b2   = (const float*)d_in[21];
    const int* esrc = ei;
    const int* edst = ei + NE;
    float* out = (float*)d_out;

    // ---- workspace layout (all regions 16B-aligned) ----
    float* bufD   = (float*)d_ws;          // mid fp32 [NN,128]      12.8 MB
    float* stats  = bufD + 3200000;        // 512 f (BN1 +0, BN2 +256)
    int* row_ptr  = (int*)(stats + 512);   // 25002
    int* cnt      = row_ptr + 25002;       // 25000
    int* col_src  = cnt + 25000;           // 425000
    int* bsum     = col_src + 425000;      // 132 (pad)
    float* fb1    = (float*)(bsum + 132);  // 768 fused bias L1
    float* fb2    = fb1 + 768;             // 768 fused bias L2
    u16* xb       = (u16*)(fb2 + 768);     // x bf16 [NN,128]         6.4 MB
    u16* XLb      = xb + 3200000;          // head-major xl [3][NN][128]  19.2 MB
    u16* XRb      = XLb + 3 * NN * 128;    // head-major xr [3][NN][128]  19.2 MB
    u16* bufCat   = XRb + 3 * NN * 128;    // [NN,768] h2|x_in bf16  38.4 MB
    u16* bufDb    = bufCat + 19200000;     // h bf16 [NN,128]         6.4 MB
    u16* WfT1     = bufDb + 3200000;       // [768][128]
    u16* W1T      = WfT1 + 98304;          // [128][384]
    u16* WfT2     = W1T + 49152;           // [768][128]
    u16* W2T      = WfT2 + 98304;          // [128][768]

    // casts + transposes + fused biases + cnt init + stats zero, one kernel
    k_cast_all<<<(CAST_TOTAL + 255) / 256, 256, 0, stream>>>(
        x, Wl1, Wr1, W1, Wl2, Wr2, W2, bl1, br1, bl2, br2,
        xb, WfT1, W1T, WfT2, W2T, fb1, fb2, cnt, stats);

    // CSR (rebuilt every call — identical work each call)
    k_count<<<(NE + 255) / 256, 256, 0, stream>>>(edst, cnt);
    k_scan1<<<98, 256, 0, stream>>>(cnt, bsum);
    k_scan2<<<1, 128, 0, stream>>>(bsum, 98);
    k_scan3<<<98, 256, 0, stream>>>(cnt, bsum, row_ptr, col_src, cnt);
    k_fill_edges<<<(NE + 255) / 256, 256, 0, stream>>>(esrc, edst, cnt, col_src);

    dim3 blk(256);
    dim3 g768(6, (NN + 127) / 128);    // BN=128
    dim3 g128(2, (NN + 127) / 128);    // BN=64
    const int GB = (NN + 3) / 4;       // gat blocks (full node range)

    // layer 1: [xl|xr] = x @ [Wl1|Wr1] -> head-major XLb/XRb
    k_gemm_bf<8, 1><<<g768, blk, 0, stream>>>(xb, WfT1, fb1, nullptr, XLb, NN, 768, DD, DD);
    for (int h = 0; h < 3; ++h)
        k_gat_h<<<GB, 256, 0, stream>>>((const u32*)XLb + (size_t)h * NN * 64,
                                        (const u32*)XRb + (size_t)h * NN * 64,
                                        att1 + h * 128, bc1 + h * 128,
                                        row_ptr, col_src,
                                        (u32*)bufCat + 192 + h * 64);

    // mid MLP + BN + relu  (A = x_in at bufCat cols 384.., lda=768)
    k_gemm_bf<4, 0><<<g128, blk, 0, stream>>>(bufCat + 384, W1T, b1, bufD, nullptr, NN, DD, HD, 768);
    k_bn_stats<<<128, 256, 0, stream>>>(bufD, stats);
    k_bn_apply<<<(NN * DD / 8 + 255) / 256, 256, 0, stream>>>(bufD, stats, g1, be1, bufDb, 0);

    // layer 2
    k_gemm_bf<8, 1><<<g768, blk, 0, stream>>>(bufDb, WfT2, fb2, nullptr, XLb, NN, 768, DD, DD);
    for (int h = 0; h < 3; ++h)
        k_gat_h<<<GB, 256, 0, stream>>>((const u32*)XLb + (size_t)h * NN * 64,
                                        (const u32*)XRb + (size_t)h * NN * 64,
                                        att2 + h * 128, bc2 + h * 128,
                                        row_ptr, col_src,
                                        (u32*)bufCat + h * 64);

    // final: concat([h2, x_in]) @ W2 + b2 as one K=768 GEMM, then BN+relu
    k_gemm_bf<4, 0><<<g128, blk, 0, stream>>>(bufCat, W2T, b2, out, nullptr, NN, DD, 768, 768);
    k_bn_stats<<<128, 256, 0, stream>>>(out, stats + 256);
    k_bn_apply<<<(NN * DD / 8 + 255) / 256, 256, 0, stream>>>(out, stats + 256, g2, be2, nullptr, 1);
}

// Round 10
// 426.841 us; speedup vs baseline: 1.2944x; 1.0812x over previous
//
#include <hip/hip_runtime.h>
#include <math.h>

#define NN 25000      // nodes
#define NE 400000     // edges
#define DD 128        // hidden dim
#define HD 384        // heads * dim
#define NEG 0.2f
#define EPS 1e-5f

typedef unsigned int u32;
typedef unsigned short u16;
typedef __attribute__((ext_vector_type(8))) short short8;   // 8 bf16 (4 VGPRs)
typedef __attribute__((ext_vector_type(4))) float floatx4;  // MFMA accumulator

// ---- bf16 helpers (RNE) ----
__device__ __forceinline__ u32 bf16_1(float x) {
    u32 u = __float_as_uint(x);
    return (u + 0x7fffu + ((u >> 16) & 1u)) >> 16;
}
__device__ __forceinline__ float blo(u32 u) { return __uint_as_float(u << 16); }
__device__ __forceinline__ float bhi(u32 u) { return __uint_as_float(u & 0xffff0000u); }

__device__ __forceinline__ void up8(uint4 u, float* f) {
    f[0] = blo(u.x); f[1] = bhi(u.x); f[2] = blo(u.y); f[3] = bhi(u.y);
    f[4] = blo(u.z); f[5] = bhi(u.z); f[6] = blo(u.w); f[7] = bhi(u.w);
}

// ---------------- CSR construction (grouped by dst) ----------------

__global__ void k_count(const int* __restrict__ dst, int* __restrict__ cnt) {
    int e = blockIdx.x * 256 + threadIdx.x;
    if (e < NE) atomicAdd(&cnt[dst[e]], 1);
}

__global__ void k_scan1(const int* __restrict__ cnt, int* __restrict__ bsum) {
    __shared__ int sh[256];
    int i = blockIdx.x * 256 + threadIdx.x;
    sh[threadIdx.x] = (i < NN) ? cnt[i] : 0;
    __syncthreads();
    for (int o = 128; o >= 1; o >>= 1) {
        if ((int)threadIdx.x < o) sh[threadIdx.x] += sh[threadIdx.x + o];
        __syncthreads();
    }
    if (threadIdx.x == 0) bsum[blockIdx.x] = sh[0];
}

__global__ void k_scan2(int* __restrict__ bsum, int nblk) {
    __shared__ int sh[128];
    int v = ((int)threadIdx.x < nblk) ? bsum[threadIdx.x] : 0;
    sh[threadIdx.x] = v;
    __syncthreads();
    for (int o = 1; o < 128; o <<= 1) {
        int t = (threadIdx.x >= (unsigned)o) ? sh[threadIdx.x - o] : 0;
        __syncthreads();
        sh[threadIdx.x] += t;
        __syncthreads();
    }
    if ((int)threadIdx.x < nblk) bsum[threadIdx.x] = sh[threadIdx.x];
}

// scan3 + self-loop fill fused
__global__ void k_scan3(const int* __restrict__ cnt, const int* __restrict__ bsum,
                        int* __restrict__ row_ptr, int* __restrict__ col_src,
                        int* __restrict__ cur) {
    __shared__ int sh[256];
    int i = blockIdx.x * 256 + threadIdx.x;
    int v = (i < NN) ? cnt[i] : 0;
    sh[threadIdx.x] = v;
    __syncthreads();
    for (int o = 1; o < 256; o <<= 1) {
        int t = (threadIdx.x >= (unsigned)o) ? sh[threadIdx.x - o] : 0;
        __syncthreads();
        sh[threadIdx.x] += t;
        __syncthreads();
    }
    int base = blockIdx.x ? bsum[blockIdx.x - 1] : 0;
    if (i < NN) {
        int incl = base + sh[threadIdx.x];
        row_ptr[i + 1] = incl;
        int p = incl - v;
        col_src[p] = i;            // self loop first
        cur[i] = p + 1;
    }
    if (i == 0) row_ptr[0] = 0;
}

__global__ void k_fill_edges(const int* __restrict__ src, const int* __restrict__ dst,
                             int* __restrict__ cur, int* __restrict__ col_src) {
    int e = blockIdx.x * 256 + threadIdx.x;
    if (e < NE) { int p = atomicAdd(&cur[dst[e]], 1); col_src[p] = src[e]; }
}

// ---------------- one cast/init kernel for everything ----------------
__global__ void k_cast_all(const float* __restrict__ x,
                           const float* __restrict__ Wl1, const float* __restrict__ Wr1,
                           const float* __restrict__ W1,
                           const float* __restrict__ Wl2, const float* __restrict__ Wr2,
                           const float* __restrict__ W2,
                           const float* __restrict__ bl1, const float* __restrict__ br1,
                           const float* __restrict__ bl2, const float* __restrict__ br2,
                           u16* __restrict__ xb, u16* __restrict__ WfT1,
                           u16* __restrict__ W1T, u16* __restrict__ WfT2,
                           u16* __restrict__ W2T,
                           float* __restrict__ fb1, float* __restrict__ fb2,
                           int* __restrict__ cnt, float* __restrict__ stats) {
    int i = blockIdx.x * 256 + threadIdx.x;
    if (i < 400000) {   // x cast, 8 elems/thread, coalesced 16B writes
        const float4* xp = (const float4*)(x + (size_t)i * 8);
        float4 a = xp[0], b = xp[1];
        uint4 w;
        w.x = bf16_1(a.x) | (bf16_1(a.y) << 16);
        w.y = bf16_1(a.z) | (bf16_1(a.w) << 16);
        w.z = bf16_1(b.x) | (bf16_1(b.y) << 16);
        w.w = bf16_1(b.z) | (bf16_1(b.w) << 16);
        *(uint4*)(xb + (size_t)i * 8) = w;
        return;
    }
    i -= 400000;
    if (i < 49152) { int k = i / 384, n = i - k * 384; WfT1[n * 128 + k] = (u16)bf16_1(Wl1[i]); return; }
    i -= 49152;
    if (i < 49152) { int k = i / 384, n = i - k * 384; WfT1[(384 + n) * 128 + k] = (u16)bf16_1(Wr1[i]); return; }
    i -= 49152;
    if (i < 49152) { int k = i / 128, n = i - k * 128; W1T[n * 384 + k] = (u16)bf16_1(W1[i]); return; }
    i -= 49152;
    if (i < 49152) { int k = i / 384, n = i - k * 384; WfT2[n * 128 + k] = (u16)bf16_1(Wl2[i]); return; }
    i -= 49152;
    if (i < 49152) { int k = i / 384, n = i - k * 384; WfT2[(384 + n) * 128 + k] = (u16)bf16_1(Wr2[i]); return; }
    i -= 49152;
    if (i < 98304) { int k = i / 128, n = i - k * 128; W2T[n * 768 + k] = (u16)bf16_1(W2[i]); return; }
    i -= 98304;
    if (i < 768) { fb1[i] = (i < 384) ? bl1[i] : br1[i - 384]; return; }
    i -= 768;
    if (i < 768) { fb2[i] = (i < 384) ? bl2[i] : br2[i - 384]; return; }
    i -= 768;
    if (i < 25000) { cnt[i] = 1; return; }   // self loop
    i -= 25000;
    if (i < 512) stats[i] = 0.f;
}
#define CAST_TOTAL (400000 + 5 * 49152 + 98304 + 1536 + 25000 + 512)

// ---------------- K=128 single-shot GEMM (the xl|xr transforms) ----------------
// C[M,768] = A[M,128] @ BT[768,128]^T + bias, head-major bf16 output.
// Stages the FULL K in one round (64 KB LDS, 16 loads/thread), ONE barrier,
// 64 MFMAs — kills the per-K-iteration vmcnt(0)+barrier drain that left the
// R7 GEMM at 3% MfmaUtil. XOR swizzle over 16 k-units: slot = c8 ^ (row&15),
// frag reads land 2-way-conflict-free (free per m136).
__global__ __launch_bounds__(256) void k_gemm_k128(
        const u16* __restrict__ A, const u16* __restrict__ BT,
        const float* __restrict__ bias, u16* __restrict__ Cb, int M) {
    __shared__ short sA[128 * 128];
    __shared__ short sB[128 * 128];
    int tid = threadIdx.x;
    int wv = tid >> 6, lane = tid & 63;
    int quad = lane >> 4, m16 = lane & 15;
    int mb = blockIdx.y * 128, nb = blockIdx.x * 128;

    // stage A+B: 2048 16B units each, 8 per thread each
#pragma unroll
    for (int j = 0; j < 8; ++j) {
        int L = j * 256 + tid;
        int r = L >> 4, c8 = (L & 15) ^ (r & 15);
        int gr = mb + r; gr = gr < M ? gr : M - 1;
        __builtin_amdgcn_global_load_lds(
            (const __attribute__((address_space(1))) void*)(A + (size_t)gr * 128 + c8 * 8),
            (__attribute__((address_space(3))) void*)(sA + (size_t)L * 8), 16, 0, 0);
    }
#pragma unroll
    for (int j = 0; j < 8; ++j) {
        int L = j * 256 + tid;
        int r = L >> 4, c8 = (L & 15) ^ (r & 15);
        __builtin_amdgcn_global_load_lds(
            (const __attribute__((address_space(1))) void*)(BT + (size_t)(nb + r) * 128 + c8 * 8),
            (__attribute__((address_space(3))) void*)(sB + (size_t)L * 8), 16, 0, 0);
    }
    __syncthreads();

    floatx4 acc[2][8];
#pragma unroll
    for (int mf = 0; mf < 2; ++mf)
#pragma unroll
        for (int nf = 0; nf < 8; ++nf)
#pragma unroll
            for (int r = 0; r < 4; ++r) acc[mf][nf][r] = 0.f;

#pragma unroll
    for (int ks = 0; ks < 4; ++ks) {
        int slot = (ks * 4 + quad) ^ m16;
        int row0 = wv * 32 + m16, row1 = row0 + 16;
        short8 a0 = *(const short8*)(sA + ((size_t)row0 * 16 + slot) * 8);
        short8 a1 = *(const short8*)(sA + ((size_t)row1 * 16 + slot) * 8);
#pragma unroll
        for (int nf = 0; nf < 8; ++nf) {
            short8 b = *(const short8*)(sB + ((size_t)(nf * 16 + m16) * 16 + slot) * 8);
            acc[0][nf] = __builtin_amdgcn_mfma_f32_16x16x32_bf16(a0, b, acc[0][nf], 0, 0, 0);
            acc[1][nf] = __builtin_amdgcn_mfma_f32_16x16x32_bf16(a1, b, acc[1][nf], 0, 0, 0);
        }
    }
    __syncthreads();

    // epilogue: bias, bf16, stage tile [128][128] u16 in sA, coalesced store
#pragma unroll
    for (int mf = 0; mf < 2; ++mf)
#pragma unroll
        for (int nf = 0; nf < 8; ++nf)
#pragma unroll
            for (int r = 0; r < 4; ++r) {
                int row = wv * 32 + mf * 16 + quad * 4 + r;
                int col = nf * 16 + m16;
                sA[row * 128 + col] = (short)bf16_1(acc[mf][nf][r] + bias[nb + col]);
            }
    __syncthreads();
    // head-major: col tile [nb,nb+128) is one head; xl heads at Cb + h*NN*128,
    // xr heads at Cb + (3+h)*NN*128, row stride 128
    int xr = nb >= 384;
    int h = (xr ? (nb - 384) : nb) >> 7;
    u16* cb = Cb + ((size_t)(xr * 3 + h) * NN) * 128;
#pragma unroll
    for (int i = 0; i < 8; ++i) {
        int u = i * 256 + tid;
        int row = u >> 4, c8 = u & 15;
        int grow = mb + row;
        if (grow < M)
            *(uint4*)(cb + (size_t)grow * 128 + c8 * 8) = *(const uint4*)(sA + (size_t)u * 8);
    }
}

// ---------------- bf16 MFMA GEMM (K-loop): C[M,N] = A[M,K] @ BT[N,K]^T ----------------
// BM=128, BN=64 (NF=4), BK=64. Used for the mid (K=384) and final (K=768)
// GEMMs with fp32 output. LDS-staged coalesced epilogue.
__global__ __launch_bounds__(256) void k_gemm_bf(
        const u16* __restrict__ A, const u16* __restrict__ BT,
        const float* __restrict__ bias,
        float* __restrict__ Cf, int M, int N, int K, int lda) {
    const int NF = 4;
    __shared__ short smem[16384];   // 32 KB
    short* sA = smem;               // 128*64
    short* sB = smem + 8192;        // 64*64
    int tid = threadIdx.x;
    int wv = tid >> 6, lane = tid & 63;
    int quad = lane >> 4, m16 = lane & 15;
    int sw = m16 & 7;
    int mb = blockIdx.y * 128, nb = blockIdx.x * 64;

    floatx4 acc[2][NF];
#pragma unroll
    for (int mf = 0; mf < 2; ++mf)
#pragma unroll
        for (int nf = 0; nf < NF; ++nf)
#pragma unroll
            for (int r = 0; r < 4; ++r) acc[mf][nf][r] = 0.f;

    for (int k0 = 0; k0 < K; k0 += 64) {
#pragma unroll
        for (int j = 0; j < 4; ++j) {
            int L = (wv * 4 + j) * 64 + lane;
            int r = L >> 3, c8 = (L & 7) ^ (r & 7);
            int gr = mb + r; gr = gr < M ? gr : M - 1;
            __builtin_amdgcn_global_load_lds(
                (const __attribute__((address_space(1))) void*)(A + (size_t)gr * lda + k0 + c8 * 8),
                (__attribute__((address_space(3))) void*)(sA + (size_t)(wv * 4 + j) * 512),
                16, 0, 0);
        }
#pragma unroll
        for (int j = 0; j < 2; ++j) {
            int L = (wv * 2 + j) * 64 + lane;
            int r = L >> 3, c8 = (L & 7) ^ (r & 7);
            __builtin_amdgcn_global_load_lds(
                (const __attribute__((address_space(1))) void*)(BT + (size_t)(nb + r) * K + k0 + c8 * 8),
                (__attribute__((address_space(3))) void*)(sB + (size_t)(wv * 2 + j) * 512),
                16, 0, 0);
        }
        __syncthreads();
#pragma unroll
        for (int ks = 0; ks < 2; ++ks) {
            int t = (ks * 4 + quad) ^ sw;
            const short* pa = sA + t * 8;
            const short* pb = sB + t * 8;
            short8 a0 = *(const short8*)(pa + (wv * 32 + m16) * 64);
            short8 a1 = *(const short8*)(pa + (wv * 32 + 16 + m16) * 64);
#pragma unroll
            for (int nf = 0; nf < NF; ++nf) {
                short8 b = *(const short8*)(pb + (nf * 16 + m16) * 64);
                acc[0][nf] = __builtin_amdgcn_mfma_f32_16x16x32_bf16(a0, b, acc[0][nf], 0, 0, 0);
                acc[1][nf] = __builtin_amdgcn_mfma_f32_16x16x32_bf16(a1, b, acc[1][nf], 0, 0, 0);
            }
        }
        __syncthreads();
    }
    // fp32 tile [128][64] staged in LDS, coalesced float4 stores
    float* fs = (float*)smem;
#pragma unroll
    for (int mf = 0; mf < 2; ++mf)
#pragma unroll
        for (int nf = 0; nf < NF; ++nf)
#pragma unroll
            for (int r = 0; r < 4; ++r) {
                int row = wv * 32 + mf * 16 + quad * 4 + r;
                int col = nf * 16 + m16;
                fs[row * 64 + col] = acc[mf][nf][r] + (bias ? bias[nb + col] : 0.f);
            }
    __syncthreads();
#pragma unroll
    for (int i = 0; i < 8; ++i) {
        int u = i * 256 + tid;
        int row = u >> 4, c4 = u & 15;
        int grow = mb + row;
        if (grow < M)
            *(float4*)(Cf + (size_t)grow * N + nb + c4 * 4) = *(const float4*)(fs + (size_t)u * 4);
    }
}

// ---------------- GATv2 aggregate, 3 heads fused (blockIdx.y = head) ----------------
// XLb/XRb head-major [3][NN][64-dword] bf16 (256B per node-head row). One wave
// per dst node; 4 groups of 16 lanes; group g handles edges e0+g, e0+g+4,...
// with depth-2 clamped prefetch. shfl_xor butterfly score reduce (LDS pipe).
// Branchless online softmax. Flash-merge of 4 group states (-1e30 sentinel).
__global__ __launch_bounds__(256) void k_gat_h(const u32* __restrict__ XLb,
                                               const u32* __restrict__ XRb,
                                               const float* __restrict__ att,
                                               const float* __restrict__ bias,
                                               const int* __restrict__ row_ptr,
                                               const int* __restrict__ col_src,
                                               u32* __restrict__ outb) {
    int h = blockIdx.y;
    const u32* XLh = XLb + (size_t)h * NN * 64;
    const u32* XRh = XRb + (size_t)h * NN * 64;
    int node = blockIdx.x * 4 + (threadIdx.x >> 6);
    int lane = threadIdx.x & 63;
    int g = lane >> 4, gl = lane & 15;

    float xr_f[8], att_f[8], acc[8];
    up8(*(const uint4*)(XRh + (size_t)node * 64 + 4 * gl), xr_f);
    *(float4*)&att_f[0] = *(const float4*)&att[h * 128 + 8 * gl];
    *(float4*)&att_f[4] = *(const float4*)&att[h * 128 + 8 * gl + 4];
#pragma unroll
    for (int k = 0; k < 8; ++k) acc[k] = 0.f;
    float m = -1e30f, l = 0.f;

    int e0 = row_ptr[node];
    int cntE = row_ptr[node + 1] - e0;
    int elast = e0 + cntE - 1;

    // depth-2 clamped prefetch
    int ea = e0 + g;     ea = ea < elast ? ea : elast;
    int eb = e0 + g + 4; eb = eb < elast ? eb : elast;
    uint4 ua = *(const uint4*)(XLh + (size_t)col_src[ea] * 64 + 4 * gl);
    uint4 ub = *(const uint4*)(XLh + (size_t)col_src[eb] * 64 + 4 * gl);

    for (int t = g; t < cntE; t += 4) {
        int en = e0 + t + 8; en = en < elast ? en : elast;
        uint4 un = *(const uint4*)(XLh + (size_t)col_src[en] * 64 + 4 * gl);

        float xv[8];
        up8(ua, xv);
        float p = 0.f;
#pragma unroll
        for (int k = 0; k < 8; ++k) {
            float v = xv[k] + xr_f[k];
            p = fmaf(fmaxf(v, NEG * v), att_f[k], p);
        }
#pragma unroll
        for (int o = 1; o <= 8; o <<= 1) p += __shfl_xor(p, o);

        float mn = fmaxf(m, p);
        float c = __expf(m - mn), w = __expf(p - mn);
        l = fmaf(l, c, w);
        m = mn;
#pragma unroll
        for (int k = 0; k < 8; ++k) acc[k] = fmaf(acc[k], c, w * xv[k]);

        ua = ub; ub = un;
    }

    // merge the 4 group states (empty group: m=-1e30, l=0, acc=0 -> adds 0)
#pragma unroll
    for (int o = 16; o <= 32; o <<= 1) {
        float mo = __shfl_xor(m, o);
        float lo = __shfl_xor(l, o);
        float mn = fmaxf(m, mo);
        float cs = __expf(m - mn);
        float co = __expf(mo - mn);
        l = l * cs + lo * co;
        m = mn;
#pragma unroll
        for (int k = 0; k < 8; ++k)
            acc[k] = acc[k] * cs + __shfl_xor(acc[k], o) * co;
    }

    if (g == 0) {   // merged state identical in all lanes of group 0
        float r = 1.f / l;
        float bv[8];
        *(float4*)&bv[0] = *(const float4*)&bias[h * 128 + 8 * gl];
        *(float4*)&bv[4] = *(const float4*)&bias[h * 128 + 8 * gl + 4];
        uint4 w;
        w.x = bf16_1(fmaf(acc[0], r, bv[0])) | (bf16_1(fmaf(acc[1], r, bv[1])) << 16);
        w.y = bf16_1(fmaf(acc[2], r, bv[2])) | (bf16_1(fmaf(acc[3], r, bv[3])) << 16);
        w.z = bf16_1(fmaf(acc[4], r, bv[4])) | (bf16_1(fmaf(acc[5], r, bv[5])) << 16);
        w.w = bf16_1(fmaf(acc[6], r, bv[6])) | (bf16_1(fmaf(acc[7], r, bv[7])) << 16);
        *(uint4*)(outb + (size_t)node * 384 + h * 64 + 4 * gl) = w;
    }
}

// ---------------- BatchNorm (axis=0 over N rows, 128 cols) ----------------

__global__ void k_bn_stats(const float* __restrict__ y, float* __restrict__ stats) {
    int col = threadIdx.x & 127;
    int half = threadIdx.x >> 7;
    float s = 0.f, q = 0.f;
    for (int r = blockIdx.x * 2 + half; r < NN; r += gridDim.x * 2) {
        float v = y[(size_t)r * DD + col];
        s += v; q += v * v;
    }
    __shared__ float sh[256], shq[256];
    sh[threadIdx.x] = s; shq[threadIdx.x] = q;
    __syncthreads();
    if (half == 0) {
        atomicAdd(&stats[col], sh[col] + sh[col + 128]);
        atomicAdd(&stats[128 + col], shq[col] + shq[col + 128]);
    }
}

// 8 elems/thread, vectorized loads+stores. finalize folded in.
__global__ void k_bn_apply(float* __restrict__ y, const float* __restrict__ stats,
                           const float* __restrict__ g, const float* __restrict__ be,
                           u16* __restrict__ yb, int wf) {
    int i = blockIdx.x * 256 + threadIdx.x;
    if (i >= NN * DD / 8) return;
    int idx = i * 8;
    int c0 = idx & 127;
    float v[8];
    *(float4*)&v[0] = *(const float4*)(y + idx);
    *(float4*)&v[4] = *(const float4*)(y + idx + 4);
    const float minv = 1.f / (float)NN;
#pragma unroll
    for (int k = 0; k < 8; ++k) {
        int c = c0 + k;
        float mu = stats[c] * minv;
        float var = stats[128 + c] * minv - mu * mu;
        float sc = g[c] * rsqrtf(var + EPS);
        float sh = be[c] - mu * sc;
        v[k] = fmaxf(fmaf(v[k], sc, sh), 0.f);
    }
    if (wf) {
        *(float4*)(y + idx) = *(const float4*)&v[0];
        *(float4*)(y + idx + 4) = *(const float4*)&v[4];
    }
    if (yb) {
        uint4 w;
        w.x = bf16_1(v[0]) | (bf16_1(v[1]) << 16);
        w.y = bf16_1(v[2]) | (bf16_1(v[3]) << 16);
        w.z = bf16_1(v[4]) | (bf16_1(v[5]) << 16);
        w.w = bf16_1(v[6]) | (bf16_1(v[7]) << 16);
        *(uint4*)(yb + idx) = w;
    }
}

// ---------------- launch ----------------

extern "C" void kernel_launch(void* const* d_in, const int* in_sizes, int n_in,
                              void* d_out, int out_size, void* d_ws, size_t ws_size,
                              hipStream_t stream) {
    const float* x    = (const float*)d_in[0];
    const int*   ei   = (const int*)d_in[1];
    const float* Wl1  = (const float*)d_in[2];
    const float* bl1  = (const float*)d_in[3];
    const float* Wr1  = (const float*)d_in[4];
    const float* br1  = (const float*)d_in[5];
    const float* att1 = (const float*)d_in[6];
    const float* bc1  = (const float*)d_in[7];
    const float* g1   = (const float*)d_in[8];
    const float* be1  = (const float*)d_in[9];
    const float* Wl2  = (const float*)d_in[10];
    const float* bl2  = (const float*)d_in[11];
    const float* Wr2  = (const float*)d_in[12];
    const float* br2  = (const float*)d_in[13];
    const float* att2 = (const float*)d_in[14];
    const float* bc2  = (const float*)d_in[15];
    const float* g2   = (const float*)d_in[16];
    const float* be2  = (const float*)d_in[17];
    const float* W1   = (const float*)d_in[18];
    const float* b1   = (const float*)d_in[19];
    const float* W2   = (const float*)d_in[20];
    const float* b2   = (const float*)d_in[21];
    const int* esrc = ei;
    const int* edst = ei + NE;
    float* out = (float*)d_out;

    // ---- workspace layout (all regions 16B-aligned) ----
    float* bufD   = (float*)d_ws;          // mid fp32 [NN,128]      12.8 MB
    float* stats  = bufD + 3200000;        // 512 f (BN1 +0, BN2 +256)
    int* row_ptr  = (int*)(stats + 512);   // 25002
    int* cnt      = row_ptr + 25002;       // 25000
    int* col_src  = cnt + 25000;           // 425000
    int* bsum     = col_src + 425000;      // 132 (pad)
    float* fb1    = (float*)(bsum + 132);  // 768 fused bias L1
    float* fb2    = fb1 + 768;             // 768 fused bias L2
    u16* xb       = (u16*)(fb2 + 768);     // x bf16 [NN,128]         6.4 MB
    u16* XLb      = xb + 3200000;          // head-major xl [3][NN][128]  19.2 MB
    u16* XRb      = XLb + 3 * NN * 128;    // head-major xr [3][NN][128]  19.2 MB (contiguous after XLb)
    u16* bufCat   = XRb + 3 * NN * 128;    // [NN,768] h2|x_in bf16  38.4 MB
    u16* bufDb    = bufCat + 19200000;     // h bf16 [NN,128]         6.4 MB
    u16* WfT1     = bufDb + 3200000;       // [768][128]
    u16* W1T      = WfT1 + 98304;          // [128][384]
    u16* WfT2     = W1T + 49152;           // [768][128]
    u16* W2T      = WfT2 + 98304;          // [128][768]

    // casts + transposes + fused biases + cnt init + stats zero, one kernel
    k_cast_all<<<(CAST_TOTAL + 255) / 256, 256, 0, stream>>>(
        x, Wl1, Wr1, W1, Wl2, Wr2, W2, bl1, br1, bl2, br2,
        xb, WfT1, W1T, WfT2, W2T, fb1, fb2, cnt, stats);

    // CSR (rebuilt every call — identical work each call)
    k_count<<<(NE + 255) / 256, 256, 0, stream>>>(edst, cnt);
    k_scan1<<<98, 256, 0, stream>>>(cnt, bsum);
    k_scan2<<<1, 128, 0, stream>>>(bsum, 98);
    k_scan3<<<98, 256, 0, stream>>>(cnt, bsum, row_ptr, col_src, cnt);
    k_fill_edges<<<(NE + 255) / 256, 256, 0, stream>>>(esrc, edst, cnt, col_src);

    dim3 blk(256);
    dim3 gK(6, (NN + 127) / 128);        // K=128 GEMM: N=768 tiles x M tiles
    dim3 g128(2, (NN + 127) / 128);      // BN=64
    dim3 gGat((NN + 3) / 4, 3);          // gat: 3 heads fused

    // layer 1: [xl|xr] = x @ [Wl1|Wr1] -> head-major XLb/XRb
    k_gemm_k128<<<gK, blk, 0, stream>>>(xb, WfT1, fb1, XLb, NN);
    k_gat_h<<<gGat, blk, 0, stream>>>((const u32*)XLb, (const u32*)XRb, att1, bc1,
                                      row_ptr, col_src, (u32*)bufCat + 192);

    // mid MLP + BN + relu  (A = x_in at bufCat cols 384.., lda=768)
    k_gemm_bf<<<g128, blk, 0, stream>>>(bufCat + 384, W1T, b1, bufD, NN, DD, HD, 768);
    k_bn_stats<<<128, 256, 0, stream>>>(bufD, stats);
    k_bn_apply<<<(NN * DD / 8 + 255) / 256, 256, 0, stream>>>(bufD, stats, g1, be1, bufDb, 0);

    // layer 2
    k_gemm_k128<<<gK, blk, 0, stream>>>(bufDb, WfT2, fb2, XLb, NN);
    k_gat_h<<<gGat, blk, 0, stream>>>((const u32*)XLb, (const u32*)XRb, att2, bc2,
                                      row_ptr, col_src, (u32*)bufCat);

    // final: concat([h2, x_in]) @ W2 + b2 as one K=768 GEMM, then BN+relu
    k_gemm_bf<<<g128, blk, 0, stream>>>(bufCat, W2T, b2, out, NN, DD, 768, 768);
    k_bn_stats<<<128, 256, 0, stream>>>(out, stats + 256);
    k_bn_apply<<<(NN * DD / 8 + 255) / 256, 256, 0, stream>>>(out, stats + 256, g2, be2, nullptr, 1);
}